// Round 9
// baseline (483.521 us; speedup 1.0000x reference)
//
#include <hip/hip_runtime.h>
#include <hip/hip_bf16.h>
#include <hip/hip_fp16.h>

using bf16 = __hip_bfloat16;

#define LQ      1024
#define NBAT    2
#define DMOD    1024
#define NHEAD   16
#define DHEAD   64
#define DFFN    4096
#define MEMLEN  1024
#define TKEY    2048
#define HDIM    1024
#define SCALE_F 0.125f
#define EPS_F   1e-5f
#define NVTILE  392   // total valid (i,j) tiles

typedef __attribute__((ext_vector_type(8))) short short8;
typedef __attribute__((ext_vector_type(4))) float f32x4;

__device__ __forceinline__ float ldf(const float* p) { return *p; }
__device__ __forceinline__ float ldf(const bf16* p) { return __bfloat162float(*p); }
__device__ __forceinline__ void stf(float* p, float v) { *p = v; }
__device__ __forceinline__ void stf(bf16* p, float v) { *p = __float2bfloat16(v); }

__device__ __forceinline__ void cpy4(bf16* dst, const float* src) {
    float4 w = *(const float4*)src;
    bf16 t[4] = {__float2bfloat16(w.x), __float2bfloat16(w.y),
                 __float2bfloat16(w.z), __float2bfloat16(w.w)};
    *(uint2*)dst = *(uint2*)t;
}
__device__ __forceinline__ void cpy4(bf16* dst, const bf16* src) {
    *(uint2*)dst = *(const uint2*)src;
}

// async global->LDS 16B: LDS dest MUST be wave-uniform; HW writes base + lane*16B
__device__ __forceinline__ void gload_lds16(const bf16* g, bf16* l) {
    __builtin_amdgcn_global_load_lds(
        (const __attribute__((address_space(1))) unsigned int*)g,
        (__attribute__((address_space(3))) unsigned int*)l, 16, 0, 0);
}

// T2 swizzle: logical (row, colE) -> LDS elem index (16B-granular XOR of row&7)
#define SWZ(row, colE) ((row) * 64 + ((colE) ^ (((row) & 7) << 3)))

// ---------------- fused fp32 -> bf16 elementwise converts (3 ranges, 1 launch) -------
__global__ __launch_bounds__(256)
void cvt3_bf16_k(const float* __restrict__ s0, bf16* __restrict__ d0, int n0,
                 const float* __restrict__ s1, bf16* __restrict__ d1, int n1,
                 const float* __restrict__ s2, bf16* __restrict__ d2, int n2)
{
    int i = (blockIdx.x * 256 + threadIdx.x) * 8;
    const float* s; bf16* d;
    if (i < n0)           { s = s0; d = d0; }
    else if (i < n0 + n1) { s = s1; d = d1; i -= n0; }
    else if (i < n0 + n1 + n2) { s = s2; d = d2; i -= n0 + n1; }
    else return;
    float4 v0 = *(const float4*)(s + i);
    float4 v1 = *(const float4*)(s + i + 4);
    bf16 t[8] = {__float2bfloat16(v0.x), __float2bfloat16(v0.y),
                 __float2bfloat16(v0.z), __float2bfloat16(v0.w),
                 __float2bfloat16(v1.x), __float2bfloat16(v1.y),
                 __float2bfloat16(v1.z), __float2bfloat16(v1.w)};
    *(uint4*)(d + i) = *(uint4*)t;
}

// ---------------- W [K][N] fp32 -> Wt [N][K] bf16, 64x64 tile body ----------------
__device__ __forceinline__ void tcvt_tile(const float* __restrict__ W,
                                          bf16* __restrict__ Wt,
                                          int K, int N, int n0, int k0, int tid,
                                          bf16 (*tile)[65])
{
    const int r = tid >> 2, cb = (tid & 3) * 16;
    #pragma unroll
    for (int e = 0; e < 16; e++)
        tile[r][cb + e] = __float2bfloat16(W[(size_t)(k0 + r) * N + n0 + cb + e]);
    __syncthreads();
    bf16 t[16];
    #pragma unroll
    for (int e = 0; e < 16; e++) t[e] = tile[cb + e][r];
    bf16* dst = Wt + (size_t)(n0 + r) * K + k0 + cb;
    *(uint4*)dst       = ((uint4*)t)[0];
    *(uint4*)(dst + 8) = ((uint4*)t)[1];
}

__global__ __launch_bounds__(256)
void tcvt_bf16_k(const float* __restrict__ W, bf16* __restrict__ Wt, int K, int N)
{
    __shared__ alignas(16) bf16 tile[64][65];
    tcvt_tile(W, Wt, K, N, blockIdx.x * 64, blockIdx.y * 64, threadIdx.x, tile);
}

// batched transpose-convert: Wkv(1024x2048) + Wrel(1024x1024) + Wq(1024x1024), K=1024
__global__ __launch_bounds__(256)
void tcvt3_k(const float* __restrict__ Wkv_, bf16* __restrict__ dkv,
             const float* __restrict__ Wrel_, bf16* __restrict__ dr,
             const float* __restrict__ Wq_, bf16* __restrict__ dq)
{
    __shared__ alignas(16) bf16 tile[64][65];
    int bid = blockIdx.x;
    const float* W; bf16* Wt; int N;
    if (bid < 512)      { W = Wkv_;  Wt = dkv; N = 2048; }
    else if (bid < 768) { W = Wrel_; Wt = dr;  N = 1024; bid -= 512; }
    else                { W = Wq_;   Wt = dq;  N = 1024; bid -= 768; }
    const int nb = N / 64;
    tcvt_tile(W, Wt, DMOD, N, (bid % nb) * 64, (bid / nb) * 64, threadIdx.x, tile);
}

// =========== 256x256-tile 8-wave GEMM, BK=64, 4-phase/K-tile schedule ===========
// 512 threads = 8 waves (2M x 4N); per-wave output 128x64 (acc[8][4] f32x4).
// LDS: 2 dbuf x 2 half x [128][64] x {A,B} = 128 KiB, T2-swizzled (pre-swizzled
// global source + XOR'd ds_read, both-sides rule).
// BUGFIX vs round 8: gload_lds LDS dest is now WAVE-UNIFORM (wid*1024 + q*512);
// HW adds lane*16B itself. The per-lane dest previously passed risked compiler
// scalarization via waterfall -> double lane offset -> OOB LDS writes (likely the
// container-killing fault).
// Schedule per K-tile t (buf b=t&1): 4 phases, each {issue gload_lds for tile t+1
// into buf b^1 (phases 0-1 only) -> ds_read quadrant frags -> 16 MFMA (setprio) ->
// barrier}; per-wave vmcnt(0) at group end (loads had 2-4 phases of MFMA cover).
template<int SPLITS, bool RELU, typename TOUT>
__device__ __forceinline__ void gemm256_body(
    const bf16* __restrict__ A, const bf16* __restrict__ Bt,
    const float* __restrict__ bias, TOUT* __restrict__ Cbase,
    int M, int N, int K, int bx, int by, int bz,
    bf16* __restrict__ As, bf16* __restrict__ Bs)   // each 2*2*8192 elems (64 KB)
{
    const int tid = threadIdx.x;
    const int wid = tid >> 6, lane = tid & 63;
    const int wm = wid >> 2, wn = wid & 3;
    const int g = lane >> 4, c16 = lane & 15;
    const int m0 = by * 256, n0 = bx * 256;
    const int klen = K / SPLITS, kstart = bz * klen;
    const int NT = klen / 64;
    TOUT* C = Cbase + (size_t)bz * M * N;

    f32x4 acc[8][4];
    #pragma unroll
    for (int mi = 0; mi < 8; mi++)
        #pragma unroll
        for (int ni = 0; ni < 4; ni++) acc[mi][ni] = (f32x4)(0.f);

    // staging: wave wid covers rows wid*16 + q*8 + (lane>>3) of each 128-row half;
    // global k-col pre-swizzled so linear LDS-DMA realizes the SWZ layout
    const int srow = wid * 16 + (lane >> 3);
    const int cc   = (((lane & 7) ^ (lane >> 3)) << 3);
    const bf16* ag = A  + (size_t)(m0 + srow) * K + kstart + cc;
    const bf16* bg = Bt + (size_t)(n0 + srow) * K + kstart + cc;
    const int lwb = wid * 1024;    // wave-uniform LDS base (elements)

    auto stageA = [&](int nb, int kt) {
        #pragma unroll
        for (int ha = 0; ha < 2; ha++)
            #pragma unroll
            for (int q = 0; q < 2; q++)
                gload_lds16(ag + (size_t)(ha * 128 + q * 8) * K + (size_t)kt * 64,
                            As + nb * 16384 + ha * 8192 + lwb + q * 512);
    };
    auto stageB = [&](int nb, int kt) {
        #pragma unroll
        for (int hb = 0; hb < 2; hb++)
            #pragma unroll
            for (int q = 0; q < 2; q++)
                gload_lds16(bg + (size_t)(hb * 128 + q * 8) * K + (size_t)kt * 64,
                            Bs + nb * 16384 + hb * 8192 + lwb + q * 512);
    };
    // reads: wave's A-half = wm (rows wm*128 + mi*16 + c16); B-half = wn>>1,
    // row-in-half = (wn&1)*64 + ni*16 + c16
    const int arb = wm * 8192;
    const int brb = (wn >> 1) * 8192;
    const int brow = (wn & 1) * 64;

    // prologue: tile 0 -> buf 0
    stageA(0, 0); stageB(0, 0);
    asm volatile("s_waitcnt vmcnt(0)" ::: "memory");
    __builtin_amdgcn_s_barrier();

    for (int t = 0; t < NT; t++) {
        const int b = t & 1, nb = b ^ 1;
        const bool pf = (t + 1 < NT);
        short8 af[4][2], bf_[2][2];
        // ---- phase 0: stage A(t+1); quadrant mi0-3 x ni0-1 ----
        if (pf) stageA(nb, t + 1);
        #pragma unroll
        for (int mi = 0; mi < 4; mi++)
            #pragma unroll
            for (int kk = 0; kk < 2; kk++)
                af[mi][kk] = *(const short8*)&As[b * 16384 + arb +
                                 SWZ(mi * 16 + c16, kk * 32 + g * 8)];
        #pragma unroll
        for (int ni = 0; ni < 2; ni++)
            #pragma unroll
            for (int kk = 0; kk < 2; kk++)
                bf_[ni][kk] = *(const short8*)&Bs[b * 16384 + brb +
                                 SWZ(brow + ni * 16 + c16, kk * 32 + g * 8)];
        __builtin_amdgcn_s_setprio(1);
        #pragma unroll
        for (int mi = 0; mi < 4; mi++)
            #pragma unroll
            for (int ni = 0; ni < 2; ni++)
                #pragma unroll
                for (int kk = 0; kk < 2; kk++)
                    acc[mi][ni] = __builtin_amdgcn_mfma_f32_16x16x32_bf16(
                                      af[mi][kk], bf_[ni][kk], acc[mi][ni], 0, 0, 0);
        __builtin_amdgcn_s_setprio(0);
        __builtin_amdgcn_s_barrier();
        // ---- phase 1: stage B(t+1); quadrant mi0-3 x ni2-3 (reuse af) ----
        if (pf) stageB(nb, t + 1);
        #pragma unroll
        for (int ni = 0; ni < 2; ni++)
            #pragma unroll
            for (int kk = 0; kk < 2; kk++)
                bf_[ni][kk] = *(const short8*)&Bs[b * 16384 + brb +
                                 SWZ(brow + (ni + 2) * 16 + c16, kk * 32 + g * 8)];
        __builtin_amdgcn_s_setprio(1);
        #pragma unroll
        for (int mi = 0; mi < 4; mi++)
            #pragma unroll
            for (int ni = 0; ni < 2; ni++)
                #pragma unroll
                for (int kk = 0; kk < 2; kk++)
                    acc[mi][ni + 2] = __builtin_amdgcn_mfma_f32_16x16x32_bf16(
                                      af[mi][kk], bf_[ni][kk], acc[mi][ni + 2], 0, 0, 0);
        __builtin_amdgcn_s_setprio(0);
        __builtin_amdgcn_s_barrier();
        // ---- phase 2: quadrant mi4-7 x ni2-3 (reuse bf_) ----
        #pragma unroll
        for (int mi = 0; mi < 4; mi++)
            #pragma unroll
            for (int kk = 0; kk < 2; kk++)
                af[mi][kk] = *(const short8*)&As[b * 16384 + arb +
                                 SWZ((mi + 4) * 16 + c16, kk * 32 + g * 8)];
        __builtin_amdgcn_s_setprio(1);
        #pragma unroll
        for (int mi = 0; mi < 4; mi++)
            #pragma unroll
            for (int ni = 0; ni < 2; ni++)
                #pragma unroll
                for (int kk = 0; kk < 2; kk++)
                    acc[mi + 4][ni + 2] = __builtin_amdgcn_mfma_f32_16x16x32_bf16(
                                      af[mi][kk], bf_[ni][kk], acc[mi + 4][ni + 2], 0, 0, 0);
        __builtin_amdgcn_s_setprio(0);
        __builtin_amdgcn_s_barrier();
        // ---- phase 3: quadrant mi4-7 x ni0-1 (reload B lo) ----
        #pragma unroll
        for (int ni = 0; ni < 2; ni++)
            #pragma unroll
            for (int kk = 0; kk < 2; kk++)
                bf_[ni][kk] = *(const short8*)&Bs[b * 16384 + brb +
                                 SWZ(brow + ni * 16 + c16, kk * 32 + g * 8)];
        __builtin_amdgcn_s_setprio(1);
        #pragma unroll
        for (int mi = 0; mi < 4; mi++)
            #pragma unroll
            for (int ni = 0; ni < 2; ni++)
                #pragma unroll
                for (int kk = 0; kk < 2; kk++)
                    acc[mi + 4][ni] = __builtin_amdgcn_mfma_f32_16x16x32_bf16(
                                      af[mi][kk], bf_[ni][kk], acc[mi + 4][ni], 0, 0, 0);
        __builtin_amdgcn_s_setprio(0);
        // group boundary: this wave's t+1 loads (issued phases 0-1) must land
        if (pf) asm volatile("s_waitcnt vmcnt(0)" ::: "memory");
        __builtin_amdgcn_s_barrier();
    }

    // epilogue: C/D layout col=lane&15, row=(lane>>4)*4+reg
    const int crow = g * 4;
    #pragma unroll
    for (int ni = 0; ni < 4; ni++) {
        const int n = n0 + wn * 64 + ni * 16 + c16;
        const float bv = (SPLITS == 1 && bias) ? bias[n] : 0.f;
        #pragma unroll
        for (int mi = 0; mi < 8; mi++) {
            #pragma unroll
            for (int reg = 0; reg < 4; reg++) {
                const int m = m0 + wm * 128 + mi * 16 + crow + reg;
                float v = acc[mi][ni][reg] + bv;
                if (RELU) v = fmaxf(v, 0.f);
                stf(C + (size_t)m * N + n, v);
            }
        }
    }
}

template<int SPLITS, bool RELU, typename TOUT>
__global__ __launch_bounds__(512)
void mgemm256_k(const bf16* __restrict__ A, const bf16* __restrict__ Bt,
                const float* __restrict__ bias, TOUT* __restrict__ Cbase,
                int M, int N, int K)
{
    __shared__ alignas(16) bf16 As[2 * 2 * 8192];
    __shared__ alignas(16) bf16 Bs[2 * 2 * 8192];
    gemm256_body<SPLITS, RELU, TOUT>(A, Bt, bias, Cbase, M, N, K,
                                     blockIdx.x, blockIdx.y, blockIdx.z, As, Bs);
}

// fused kv/r/q projections at 256^2: 128 + 64 + 32 = 224 blocks of 512 threads
__global__ __launch_bounds__(512)
void proj3_256_k(const bf16* __restrict__ catc, const bf16* __restrict__ wkvt,
                 bf16* __restrict__ kvb,
                 const bf16* __restrict__ posc, const bf16* __restrict__ wrelt,
                 bf16* __restrict__ rb,
                 const bf16* __restrict__ xb, const bf16* __restrict__ wqt,
                 float* __restrict__ qb)
{
    __shared__ alignas(16) bf16 As[2 * 2 * 8192];
    __shared__ alignas(16) bf16 Bs[2 * 2 * 8192];
    int bid = blockIdx.x;
    if (bid < 128) {
        gemm256_body<1, false, bf16>(catc, wkvt, nullptr, kvb,
                                     TKEY * NBAT, 2 * HDIM, DMOD,
                                     bid & 7, bid >> 3, 0, As, Bs);
    } else if (bid < 192) {
        bid -= 128;
        gemm256_body<1, false, bf16>(posc, wrelt, nullptr, rb,
                                     TKEY * NBAT, HDIM, DMOD,
                                     bid & 3, bid >> 2, 0, As, Bs);
    } else {
        bid -= 192;
        gemm256_body<1, false, float>(xb, wqt, nullptr, qb,
                                      LQ * NBAT, HDIM, DMOD,
                                      bid & 3, bid >> 2, 0, As, Bs);
    }
}

// ---------------- 128x128 GEMM body (dbuf + T2 swizzle) — mid-tier path -----------
template<int SPLITS, bool RELU, typename TOUT>
__device__ __forceinline__ void gemm128_body(
    const bf16* __restrict__ A, const bf16* __restrict__ Bt,
    const float* __restrict__ bias, TOUT* __restrict__ Cbase,
    int M, int N, int K, int bx, int by, int bz,
    bf16* __restrict__ As, bf16* __restrict__ Bs)
{
    const int tid  = threadIdx.x;
    const int wave = tid >> 6, lane = tid & 63;
    const int m0 = by * 128, n0 = bx * 128;
    const int g = lane >> 4, c16 = lane & 15;
    const int wr = (wave >> 1) * 64, wc = (wave & 1) * 64;

    const int klen   = K / SPLITS;
    const int kstart = bz * klen;
    TOUT* C = Cbase + (size_t)bz * M * N;

    f32x4 acc[4][4];
    #pragma unroll
    for (int mi = 0; mi < 4; mi++)
        #pragma unroll
        for (int ni = 0; ni < 4; ni++) acc[mi][ni] = (f32x4)(0.f);

    const int r0 = (wave << 5) + (lane >> 3);
    const int cc = (((lane & 7) ^ (lane >> 3)) << 3);
    const bf16* agp = A  + (size_t)(m0 + r0) * K + kstart + cc;
    const bf16* bgp = Bt + (size_t)(n0 + r0) * K + kstart + cc;
    const int lb = wave * 2048;

    #pragma unroll
    for (int q = 0; q < 4; q++) {
        gload_lds16(agp + (size_t)(q * 8) * K, As + lb + q * 512);
        gload_lds16(bgp + (size_t)(q * 8) * K, Bs + lb + q * 512);
    }

    int cur = 0;
    for (int k0 = 0; k0 < klen; k0 += 64) {
        if (k0 + 64 < klen) {
            #pragma unroll
            for (int q = 0; q < 4; q++) {
                gload_lds16(agp + k0 + 64 + (size_t)(q * 8) * K,
                            As + (cur ^ 1) * 8192 + lb + q * 512);
                gload_lds16(bgp + k0 + 64 + (size_t)(q * 8) * K,
                            Bs + (cur ^ 1) * 8192 + lb + q * 512);
            }
            asm volatile("s_waitcnt vmcnt(8)" ::: "memory");
        } else {
            asm volatile("s_waitcnt vmcnt(0)" ::: "memory");
        }
        __builtin_amdgcn_s_barrier();
        short8 af[4][2], bfr[4][2];
        #pragma unroll
        for (int mi = 0; mi < 4; mi++) {
            const int row = wr + mi * 16 + c16;
            af[mi][0] = *(const short8*)&As[cur * 8192 + SWZ(row, g * 8)];
            af[mi][1] = *(const short8*)&As[cur * 8192 + SWZ(row, 32 + g * 8)];
        }
        #pragma unroll
        for (int ni = 0; ni < 4; ni++) {
            const int row = wc + ni * 16 + c16;
            bfr[ni][0] = *(const short8*)&Bs[cur * 8192 + SWZ(row, g * 8)];
            bfr[ni][1] = *(const short8*)&Bs[cur * 8192 + SWZ(row, 32 + g * 8)];
        }
        #pragma unroll
        for (int mi = 0; mi < 4; mi++)
            #pragma unroll
            for (int ni = 0; ni < 4; ni++) {
                acc[mi][ni] = __builtin_amdgcn_mfma_f32_16x16x32_bf16(
                                  af[mi][0], bfr[ni][0], acc[mi][ni], 0, 0, 0);
                acc[mi][ni] = __builtin_amdgcn_mfma_f32_16x16x32_bf16(
                                  af[mi][1], bfr[ni][1], acc[mi][ni], 0, 0, 0);
            }
        __builtin_amdgcn_s_barrier();
        cur ^= 1;
    }

    const int crow = g * 4;
    #pragma unroll
    for (int ni = 0; ni < 4; ni++) {
        const int n = n0 + wc + ni * 16 + c16;
        const float bv = (SPLITS == 1 && bias) ? bias[n] : 0.f;
        #pragma unroll
        for (int mi = 0; mi < 4; mi++) {
            #pragma unroll
            for (int reg = 0; reg < 4; reg++) {
                const int m = m0 + wr + mi * 16 + crow + reg;
                float v = acc[mi][ni][reg] + bv;
                if (RELU) v = fmaxf(v, 0.f);
                stf(C + (size_t)m * N + n, v);
            }
        }
    }
}

template<int SPLITS, bool RELU, typename TOUT>
__global__ __launch_bounds__(256)
void mgemm128_k(const bf16* __restrict__ A, const bf16* __restrict__ Bt,
                const float* __restrict__ bias, TOUT* __restrict__ Cbase,
                int M, int N, int K)
{
    __shared__ alignas(16) bf16 As[2 * 128 * 64];
    __shared__ alignas(16) bf16 Bs[2 * 128 * 64];
    gemm128_body<SPLITS, RELU, TOUT>(A, Bt, bias, Cbase, M, N, K,
                                     blockIdx.x, blockIdx.y, blockIdx.z, As, Bs);
}

// fused kv/r/q projections at 128^2 (mid-tier path)
__global__ __launch_bounds__(256)
void proj3_k(const bf16* __restrict__ catc, const bf16* __restrict__ wkvt,
             bf16* __restrict__ kvb,
             const bf16* __restrict__ posc, const bf16* __restrict__ wrelt,
             bf16* __restrict__ rb,
             const bf16* __restrict__ xb, const bf16* __restrict__ wqt,
             float* __restrict__ qb)
{
    __shared__ alignas(16) bf16 As[2 * 128 * 64];
    __shared__ alignas(16) bf16 Bs[2 * 128 * 64];
    int bid = blockIdx.x;
    if (bid < 512) {
        gemm128_body<1, false, bf16>(catc, wkvt, nullptr, kvb,
                                     TKEY * NBAT, 2 * HDIM, DMOD,
                                     bid & 15, bid >> 4, 0, As, Bs);
    } else if (bid < 768) {
        bid -= 512;
        gemm128_body<1, false, bf16>(posc, wrelt, nullptr, rb,
                                     TKEY * NBAT, HDIM, DMOD,
                                     bid & 7, bid >> 3, 0, As, Bs);
    } else {
        bid -= 768;
        gemm128_body<1, false, float>(xb, wqt, nullptr, qb,
                                      LQ * NBAT, HDIM, DMOD,
                                      bid & 7, bid >> 3, 0, As, Bs);
    }
}

// ---------------- MFMA GEMM, 64x64 tile (fallback path, fp32 weights) ----------------
template<typename TA, typename TOUT, bool RELU>
__global__ __launch_bounds__(256)
void mgemm64_k(const TA* __restrict__ A0, const TA* __restrict__ A1, int rowsplit,
               const float* __restrict__ Bw, const float* __restrict__ bias,
               TOUT* __restrict__ C, int M, int N, int K)
{
    __shared__ alignas(16) bf16 As[64][72];
    __shared__ alignas(16) bf16 Bs[64][72];
    const int tid  = threadIdx.x;
    const int m0   = blockIdx.y * 64;
    const int n0   = blockIdx.x * 64;
    const int wave = tid >> 6, lane = tid & 63;
    const int g = lane >> 4, c16 = lane & 15;

    f32x4 acc[4];
    #pragma unroll
    for (int nt = 0; nt < 4; nt++) acc[nt] = (f32x4)(0.f);

    const int ar = tid >> 2, akc = (tid & 3) * 16;
    const int grow = m0 + ar;
    const TA* Arow = (grow < rowsplit) ? (A0 + (size_t)grow * K)
                                       : (A1 + (size_t)(grow - rowsplit) * K);
    const int bn = tid & 63, bkb = (tid >> 6) * 16;
    const float* Bcol = Bw + n0 + bn;

    for (int k0 = 0; k0 < K; k0 += 64) {
        cpy4(&As[ar][akc],      Arow + k0 + akc);
        cpy4(&As[ar][akc + 4],  Arow + k0 + akc + 4);
        cpy4(&As[ar][akc + 8],  Arow + k0 + akc + 8);
        cpy4(&As[ar][akc + 12], Arow + k0 + akc + 12);
        {
            bf16 t16[16];
            #pragma unroll
            for (int e = 0; e < 16; e++)
                t16[e] = __float2bfloat16(Bcol[(size_t)(k0 + bkb + e) * N]);
            *(uint4*)&Bs[bn][bkb]     = *(uint4*)&t16[0];
            *(uint4*)&Bs[bn][bkb + 8] = *(uint4*)&t16[8];
        }
        __syncthreads();
        const short8 a0 = *(const short8*)&As[wave * 16 + c16][g * 8];
        const short8 a1 = *(const short8*)&As[wave * 16 + c16][32 + g * 8];
        #pragma unroll
        for (int nt = 0; nt < 4; nt++) {
            acc[nt] = __builtin_amdgcn_mfma_f32_16x16x32_bf16(
                          a0, *(const short8*)&Bs[nt * 16 + c16][g * 8], acc[nt], 0, 0, 0);
            acc[nt] = __builtin_amdgcn_mfma_f32_16x16x32_bf16(
                          a1, *(const short8*)&Bs[nt * 16 + c16][32 + g * 8], acc[nt], 0, 0, 0);
        }
        __syncthreads();
    }

    const int crow = (lane >> 4) * 4, ccol = lane & 15;
    #pragma unroll
    for (int nt = 0; nt < 4; nt++) {
        const int n = n0 + nt * 16 + ccol;
        const float bv = bias ? bias[n] : 0.f;
        #pragma unroll
        for (int rr = 0; rr < 4; rr++) {
            const int m = m0 + wave * 16 + crow + rr;
            float v = acc[nt][rr] + bv;
            if (RELU) v = fmaxf(v, 0.f);
            stf(C + (size_t)m * N + n, v);
        }
    }
}

union Frag8 { bf16 h[8]; short8 v; };

// ============ single-sweep online-softmax MFMA attention (2 barriers/tile) ============
template<bool WRSC>
__global__ __launch_bounds__(256)
void flash_attn_k(const float* __restrict__ q, const bf16* __restrict__ kv,
                  const bf16* __restrict__ rg, const float* __restrict__ ub,
                  const float* __restrict__ vb,
                  float* __restrict__ m_arr, float* __restrict__ l_arr,
                  bf16* __restrict__ vec, __half* __restrict__ scr)
{
    __shared__ alignas(16) bf16 Ks[64][72];
    __shared__ alignas(16) bf16 Rs[128][72];
    __shared__ alignas(16) bf16 Vt[64][72];
    __shared__ alignas(16) bf16 BDs[64][136];

    const int itile = (blockIdx.y < (NBAT * NHEAD / 2))
                          ? blockIdx.x : (gridDim.x - 1 - blockIdx.x);
    const int i0 = itile * 64;
    const int bh = blockIdx.y;
    const int b = bh >> 4, h = bh & 15;
    const int tid = threadIdx.x;
    const int wave = tid >> 6, lane = tid & 63;
    const int g = lane >> 4, c16 = lane & 15;
    const int dib = wave * 16 + g * 4;
    const int tbase = itile * 17 + itile * (itile - 1) / 2;

    Frag8 fu0, fu1, fv0, fv1;
    {
        const float* qrow = q + ((size_t)(i0 + wave * 16 + c16) * NBAT + b) * HDIM + h * DHEAD;
        const float* ubp = ub + h * DHEAD;
        const float* vbp = vb + h * DHEAD;
        #pragma unroll
        for (int e = 0; e < 8; e++) {
            float q0 = qrow[g * 8 + e], q1 = qrow[32 + g * 8 + e];
            fu0.h[e] = __float2bfloat16(q0 + ubp[g * 8 + e]);
            fu1.h[e] = __float2bfloat16(q1 + ubp[32 + g * 8 + e]);
            fv0.h[e] = __float2bfloat16(q0 + vbp[g * 8 + e]);
            fv1.h[e] = __float2bfloat16(q1 + vbp[32 + g * 8 + e]);
        }
    }

    float mrow[4] = {-3e38f, -3e38f, -3e38f, -3e38f};
    float lrow[4] = {0.f, 0.f, 0.f, 0.f};
    f32x4 Oacc[4];
    #pragma unroll
    for (int nt = 0; nt < 4; nt++) Oacc[nt] = (f32x4)(0.f);

    const int ntiles = i0 / 64 + 17;

    for (int t = 0; t < ntiles; t++) {
        const int j0 = t * 64;
        const int jj0 = j0 + (LQ - 64) - i0;
        __half* scp = nullptr;
        if (WRSC) scp = scr + ((size_t)bh * NVTILE + tbase + t) * 4096;
        // ---- phase 1: stage K, R, V ----
        {
            const int row = tid >> 2, dbase = (tid & 3) * 16;
            const bf16* src = kv + ((size_t)(j0 + row) * NBAT + b) * (2 * HDIM)
                                 + h * DHEAD + dbase;
            *(uint4*)&Ks[row][dbase]     = *(const uint4*)src;
            *(uint4*)&Ks[row][dbase + 8] = *(const uint4*)(src + 8);
        }
        {
            const int row = tid >> 1, dbase = (tid & 1) * 32;
            const int jj = jj0 + row;
            if (jj < TKEY) {
                const bf16* src = rg + ((size_t)jj * NBAT + b) * HDIM + h * DHEAD + dbase;
                #pragma unroll
                for (int u = 0; u < 4; u++)
                    *(uint4*)&Rs[row][dbase + u * 8] = *(const uint4*)(src + u * 8);
            } else {
                const uint4 z = make_uint4(0, 0, 0, 0);
                #pragma unroll
                for (int u = 0; u < 4; u++)
                    *(uint4*)&Rs[row][dbase + u * 8] = z;
            }
        }
        {
            const int j = tid & 63, dbase = (tid >> 6) * 16;
            const bf16* src = kv + ((size_t)(j0 + j) * NBAT + b) * (2 * HDIM)
                                 + HDIM + h * DHEAD + dbase;
            bf16 tmp[16];
            *(uint4*)&tmp[0] = *(const uint4*)src;
            *(uint4*)&tmp[8] = *(const uint4*)(src + 8);
            #pragma unroll
            for (int e = 0; e < 16; e++) Vt[dbase + e][j] = tmp[e];
        }
        __syncthreads();
        // ---- QK^T (AC) ----
        f32x4 ac[4];
        #pragma unroll
        for (int nt = 0; nt < 4; nt++) {
            ac[nt] = (f32x4)(0.f);
            ac[nt] = __builtin_amdgcn_mfma_f32_16x16x32_bf16(
                         fu0.v, *(const short8*)&Ks[nt * 16 + c16][g * 8], ac[nt], 0, 0, 0);
            ac[nt] = __builtin_amdgcn_mfma_f32_16x16x32_bf16(
                         fu1.v, *(const short8*)&Ks[nt * 16 + c16][32 + g * 8], ac[nt], 0, 0, 0);
        }
        // ---- BD (rel) -> BDs stripe (intra-wave round-trip) ----
        #pragma unroll
        for (int nt = 0; nt < 8; nt++) {
            f32x4 bd = (f32x4)(0.f);
            bd = __builtin_amdgcn_mfma_f32_16x16x32_bf16(
                     fv0.v, *(const short8*)&Rs[nt * 16 + c16][g * 8], bd, 0, 0, 0);
            bd = __builtin_amdgcn_mfma_f32_16x16x32_bf16(
                     fv1.v, *(const short8*)&Rs[nt * 16 + c16][32 + g * 8], bd, 0, 0, 0);
            #pragma unroll
            for (int reg = 0; reg < 4; reg++)
                BDs[dib + reg][nt * 16 + c16] = __float2bfloat16(bd[reg]);
        }
        // ---- scores (+ packed fp16 cache) + online softmax ----
        float sv[4][4];
        #pragma unroll
        for (int reg = 0; reg < 4; reg++) {
            const int di = dib + reg;
            const int colbase = 63 - di;
            __half hv[4];
            #pragma unroll
            for (int nt = 0; nt < 4; nt++) {
                const int dj = nt * 16 + c16;
                float s = (ac[nt][reg] +
                           __bfloat162float(BDs[di][colbase + dj])) * SCALE_F;
                if (j0 + dj > i0 + di + MEMLEN) s = -1e30f;
                sv[nt][reg] = s;
                if (WRSC) hv[nt] = __float2half(s);
            }
            if (WRSC) *(uint2*)&scp[di * 64 + c16 * 4] = *(uint2*)hv;
        }
        #pragma unroll
        for (int reg = 0; reg < 4; reg++) {
            float tm = fmaxf(fmaxf(sv[0][reg], sv[1][reg]),
                             fmaxf(sv[2][reg], sv[3][reg]));
            #pragma unroll
            for (int mk = 1; mk < 16; mk <<= 1)
                tm = fmaxf(tm, __shfl_xor(tm, mk));
            const float nm = fmaxf(mrow[reg], tm);
            const float alpha = __expf(mrow[reg] - nm);
            float ev[4];
            #pragma unroll
            for (int nt = 0; nt < 4; nt++) ev[nt] = __expf(sv[nt][reg] - nm);
            float ps = ev[0] + ev[1] + ev[2] + ev[3];
            #pragma unroll
            for (int mk = 1; mk < 16; mk <<= 1)
                ps += __shfl_xor(ps, mk);
            lrow[reg] = lrow[reg] * alpha + ps;
            mrow[reg] = nm;
            #pragma unroll
            for (int nt = 0; nt < 4; nt++) {
                Oacc[nt][reg] *= alpha;
                BDs[dib + reg][nt * 16 + c16] = __float2bfloat16(ev[nt]);
            }
        }
        // ---- PV ----
        short8 p0 = *(const short8*)&BDs[wave * 16 + c16][g * 8];
        short8 p1 = *(const short8*)&BDs[wave * 16 + c16][32 + g * 8];
        #pragma unroll
        for (int nt = 0; nt < 4; nt++) {
            Oacc[nt] = __builtin_amdgcn_mfma_f32_16x16x32_bf16(
                           p0, *(const short8*)&Vt[nt * 16 + c16][g * 8], Oacc[nt], 0, 0, 0);
            Oacc[nt] = __builtin_amdgcn_mfma_f32_16x16x32_bf16(
                           p1, *(const short8*)&Vt[nt * 16 + c16][32 + g * 8], Oacc[nt], 0, 0, 0);
        }
        __syncthreads();
    }

    float invl[4];
    #pragma unroll
    for (int reg = 0; reg < 4; reg++) invl[reg] = 1.f / lrow[reg];
    #pragma unroll
    for (int nt = 0; nt < 4; nt++)
        #pragma unroll
        for (int reg = 0; reg < 4; reg++)
            vec[((size_t)(i0 + dib + reg) * NBAT + b) * HDIM + h * DHEAD + nt * 16 + c16]
                = __float2bfloat16(Oacc[nt][reg] * invl[reg]);
    if (c16 == 0) {
        #pragma unroll
        for (int reg = 0; reg < 4; reg++) {
            const int idx = ((i0 + dib + reg) * NBAT + b) * NHEAD + h;
            m_arr[idx] = mrow[reg];
            l_arr[idx] = lrow[reg];
        }
    }
}

// ============ attn matrix from cached scores — no atomics ==========
__global__ __launch_bounds__(256)
void attn_sum2_k(const __half* __restrict__ scr, const float* __restrict__ m_arr,
                 const float* __restrict__ l_arr, float* __restrict__ attn)
{
    int f = blockIdx.x, it = 0, base = 0;
    for (it = 0; it < 16; it++) {
        const int cnt = it + 17;
        if (f < base + cnt) break;
        base += cnt;
    }
    const int i0 = it * 64;
    const int j0 = (f - base) * 64;
    const int tid = threadIdx.x;
    const int row = blockIdx.y * 32 + (tid >> 3);
    const int pb = (tid & 7) * 8;
    const int i = i0 + row;

    float acc[8] = {0.f, 0.f, 0.f, 0.f, 0.f, 0.f, 0.f, 0.f};

    for (int bh = 0; bh < NBAT * NHEAD; bh++) {
        const int b = bh >> 4, h = bh & 15;
        const __half* sp = scr + ((size_t)bh * NVTILE + blockIdx.x) * 4096 + row * 64 + pb;
        const int idx = (i * NBAT + b) * NHEAD + h;
        const float mi = m_arr[idx];
        const float il = 1.f / l_arr[idx];
        union { uint4 v; __half hx[8]; } u;
        u.v = *(const uint4*)sp;
        #pragma unroll
        for (int e = 0; e < 8; e++)
            acc[e] += __expf(__half2float(u.hx[e]) - mi) * il;
    }
    const float inv = 1.f / (NBAT * NHEAD);
    #pragma unroll
    for (int e = 0; e < 8; e++) {
        const int p = pb + e;
        const int j = (p & 3) * 16 + (p >> 2);
        attn[(size_t)i * TKEY + j0 + j] = acc[e] * inv;
    }
}

// ============ attn matrix via MFMA (mid-tier fallback; atomic-accumulating) ==========
__global__ __launch_bounds__(256)
void attn_mat4_k(const float* __restrict__ q, const bf16* __restrict__ kv,
                 const bf16* __restrict__ rg, const float* __restrict__ ub,
                 const float* __restrict__ vb, const float* __restrict__ m_arr,
                 const float* __restrict__ l_arr, float* __restrict__ attn)
{
    int f = blockIdx.x, it = 0, base = 0;
    for (it = 0; it < 16; it++) {
        const int cnt = it + 17;
        if (f < base + cnt) break;
        base += cnt;
    }
    const int i0 = it * 64;
    const int j0 = (f - base) * 64;
    const int bhb = blockIdx.y * 16;

    __shared__ alignas(16) bf16 Ks[64][72];
    __shared__ alignas(16) bf16 Rs[128][72];
    __shared__ alignas(16) bf16 BDs[64][136];
    const int tid = threadIdx.x;
    const int wave = tid >> 6, lane = tid & 63;
    const int g = lane >> 4, c16 = lane & 15;
    const int dib = wave * 16 + g * 4;
    const int jj0 = j0 + (LQ - 64) - i0;
    float psum[4][4] = {};

    for (int bh = bhb; bh < bhb + 16; bh++) {
        const int b = bh >> 4, h = bh & 15;
        Frag8 fu0, fu1, fv0, fv1;
        {
            const float* qrow = q + ((size_t)(i0 + wave * 16 + c16) * NBAT + b) * HDIM + h * DHEAD;
            const float* ubp = ub + h * DHEAD;
            const float* vbp = vb + h * DHEAD;
            #pragma unroll
            for (int e = 0; e < 8; e++) {
                float q0 = qrow[g * 8 + e], q1 = qrow[32 + g * 8 + e];
                fu0.h[e] = __float2bfloat16(q0 + ubp[g * 8 + e]);
                fu1.h[e] = __float2bfloat16(q1 + ubp[32 + g * 8 + e]);
                fv0.h[e] = __float2bfloat16(q0 + vbp[g * 8 + e]);
                fv1.h[e] = __float2bfloat16(q1 + vbp[32 + g * 8 + e]);
            }
        }
        {
            const int row = tid >> 2, dbase = (tid & 3) * 16;
            const bf16* src = kv + ((size_t)(j0 + row) * NBAT + b) * (2 * HDIM)
                                 + h * DHEAD + dbase;
            *(uint4*)&Ks[row][dbase]     = *(const uint4*)src;
            *(uint4*)&Ks[row][dbase + 8] = *(const uint4*)(src + 8);
        }
        {
            const int row = tid >> 1, dbase = (tid & 1) * 32;
            const int jj = jj0 + row;
            if (jj < TKEY) {
                const bf16* src = rg + ((size_t)jj * NBAT + b) * HDIM + h * DHEAD + dbase;
                #pragma unroll
                for (int u = 0; u < 4; u++)
                    *(uint4*)&Rs[row][dbase + u * 8] = *(const uint4*)(src + u * 8);
            } else {
                const uint4 z = make_uint4(0, 0, 0, 0);
                #pragma unroll
                for (int u = 0; u < 4; u++)
                    *(uint4*)&Rs[row][dbase + u * 8] = z;
            }
        }
        __syncthreads();
        f32x4 ac[4];
        #pragma unroll
        for (int nt = 0; nt < 4; nt++) {
            ac[nt] = (f32x4)(0.f);
            ac[nt] = __builtin_amdgcn_mfma_f32_16x16x32_bf16(
                         fu0.v, *(const short8*)&Ks[nt * 16 + c16][g * 8], ac[nt], 0, 0, 0);
            ac[nt] = __builtin_amdgcn_mfma_f32_16x16x32_bf16(
                         fu1.v, *(const short8*)&Ks[nt * 16 + c16][32 + g * 8], ac[nt], 0, 0, 0);
        }
        #pragma unroll
        for (int nt = 0; nt < 8; nt++) {
            f32x4 bd = (f32x4)(0.f);
            bd = __builtin_amdgcn_mfma_f32_16x16x32_bf16(
                     fv0.v, *(const short8*)&Rs[nt * 16 + c16][g * 8], bd, 0, 0, 0);
            bd = __builtin_amdgcn_mfma_f32_16x16x32_bf16(
                     fv1.v, *(const short8*)&Rs[nt * 16 + c16][32 + g * 8], bd, 0, 0, 0);
            #pragma unroll
            for (int reg = 0; reg < 4; reg++)
                BDs[dib + reg][nt * 16 + c16] = __float2bfloat16(bd[reg]);
        }
        #pragma unroll
        for (int reg = 0; reg < 4; reg++) {
            const int di = dib + reg;
            const int colbase = 63 - di;
            const int idx = ((i0 + di) * NBAT + b) * NHEAD + h;
            const float mi = m_arr[idx];
            const float il = 1.f / l_arr[idx];
            #pragma unroll
            for (int nt = 0; nt < 4; nt++) {
                const int dj = nt * 16 + c16;
                float s = (ac[nt][reg] +
                           __bfloat162float(BDs[di][colbase + dj])) * SCALE_F;
                float p = (j0 + dj > i0 + di + MEMLEN) ? 0.f : __expf(s - mi) * il;
                psum[nt][reg] += p;
            }
        }
        __syncthreads();
    }
    const float inv = 1.f / (NBAT * NHEAD);
    #pragma unroll
    for (int nt = 0; nt < 4; nt++)
        #pragma unroll
        for (int reg = 0; reg < 4; reg++)
            atomicAdd(&attn[(size_t)(i0 + dib + reg) * TKEY + j0 + nt * 16 + c16],
                      psum[nt][reg] * inv);
}

// ---------------- fused residual + LayerNorm ----------------
template<typename T1, typename T2, typename TOUT>
__global__ __launch_bounds__(256)
void ln_k(const T1* __restrict__ a, const T2* __restrict__ c,
          const float* __restrict__ g, const float* __restrict__ bb,
          TOUT* __restrict__ out)
{
    const int row = blockIdx.x;
    const int tid = threadIdx.x;
    const size_t base = (size_t)row * DMOD;
    float vals[4];
    float s = 0.f, sq = 0.f;
    #pragma unroll
    for (int t = 0; t < 4; t++) {
        const int dcol = tid + t * 256;
        float v = ldf(a + base + dcol) + ldf(c + base + dcol);
        vals[t] = v; s += v; sq += v * v;
    }
    __shared__ float rs[256], rq[256];
    rs[tid] = s; rq[tid] = sq;
    __syncthreads();
    for (int st = 128; st > 0; st >>= 1) {
        if (tid < st) { rs[tid] += rs[tid + st]; rq[tid] += rq[tid + st]; }
        __syncthreads();
    }
    const float mean = rs[0] / DMOD;
    const float var = rq[0] / DMOD - mean * mean;
    const float rstd = rsqrtf(fmaxf(var, 0.f) + EPS_F);
    #pragma unroll
    for (int t = 0; t < 4; t++) {
        const int dcol = tid + t * 256;
        float v = (vals[t] - mean) * rstd * g[dcol] + bb[dcol];
        stf(out + base + dcol, v);
    }
}

// ---------------- residual + NP split-K fp32 partials (+optional bias) + LayerNorm ----
template<typename TA, int NP, bool HASB, typename TOUT>
__global__ __launch_bounds__(256)
void lnp_k(const TA* __restrict__ a, const float* __restrict__ part, size_t pstride,
           const float* __restrict__ biasvec, const float* __restrict__ g,
           const float* __restrict__ bb, TOUT* __restrict__ out)
{
    const int row = blockIdx.x;
    const int tid = threadIdx.x;
    const size_t base = (size_t)row * DMOD;
    float vals[4];
    float s = 0.f, sq = 0.f;
    #pragma unroll
    for (int t = 0; t < 4; t++) {
        const int dcol = tid + t * 256;
        float v = ldf(a + base + dcol);
        #pragma unroll
        for (int p = 0; p < NP; p++) v += part[(size_t)p * pstride + base + dcol];
        if (HASB) v += biasvec[dcol];
        vals[t] = v; s += v; sq += v * v;
    }
    __shared__ float rs[256], rq[256];
    rs[tid] = s; rq[tid] = sq;
    __syncthreads();
    for (int st = 128; st > 0; st >>= 1) {
        if (tid < st) { rs[tid] += rs[tid + st]; rq[tid] += rq[tid + st]; }
        __syncthreads();
    }
    const float mean = rs[0] / DMOD;
    const float var = rq[0] / DMOD - mean * mean;
    const float rstd = rsqrtf(fmaxf(var, 0.f) + EPS_F);
    #pragma unroll
    for (int t = 0; t < 4; t++) {
        const int dcol = tid + t * 256;
        float v = (vals[t] - mean) * rstd * g[dcol] + bb[dcol];
        stf(out + base + dcol, v);
    }
}

__global__ void fill_zero_k(float* __restrict__ p, int n) {
    int i = blockIdx.x * 256 + threadIdx.x;
    if (i < n) p[i] = 0.f;
}

extern "C" void kernel_launch(void* const* d_in, const int* in_sizes, int n_in,
                              void* d_out, int out_size, void* d_ws, size_t ws_size,
                              hipStream_t stream)
{
    const float* x    = (const float*)d_in[0];
    const float* pos  = (const float*)d_in[1];
    const float* ub   = (const float*)d_in[2];
    const float* vb   = (const float*)d_in[3];
    const float* memp = (const float*)d_in[4];
    const float* Wq   = (const float*)d_in[5];
    const float* Wkv  = (const float*)d_in[6];
    const float* Wo   = (const float*)d_in[7];
    const float* Wrel = (const float*)d_in[8];
    const float* ln1g = (const float*)d_in[9];
    const float* ln1b = (const float*)d_in[10];
    const float* W1   = (const float*)d_in[11];
    const float* b1   = (const float*)d_in[12];
    const float* W2   = (const float*)d_in[13];
    const float* b2   = (const float*)d_in[14];
    const float* ln2g = (const float*)d_in[15];
    const float* ln2b = (const float*)d_in[16];

    // ---- workspace, lifetime-aliased ----
    char* wsb = (char*)d_ws;
    const size_t MB = 1048576;
    bf16*  kvb   = (bf16*)(wsb + 0);
    bf16*  h1    = (bf16*)(wsb + 0);
    bf16*  rb    = (bf16*)(wsb + 16 * MB);
    bf16*  aout  = (bf16*)(wsb + 16 * MB);
    bf16*  f2o   = (bf16*)(wsb + 16 * MB);
    bf16*  out1  = (bf16*)(wsb + 20 * MB);
    bf16*  vecb  = (bf16*)(wsb + 24 * MB);
    float* m_arr = (float*)(wsb + 28 * MB);
    float* l_arr = (float*)(wsb + 28 * MB + 131072);
    const size_t ws_need_old = 28 * MB + 262144;
    bf16*  catc  = (bf16*)(wsb + 30 * MB);
    bf16*  posc  = (bf16*)(wsb + 38 * MB);
    float* part2 = (float*)(wsb + 30 * MB);
    bf16*  wscr  = (bf16*)(wsb + 46 * MB);
    const size_t ws_need_new = 54 * MB;
    __half* scrh = (__half*)(wsb + 54 * MB);   // fp16 score cache, 98 MB
    float* part4 = (float*)(wsb + 54 * MB);    // 4x8MB fp32 split-K partials
                                               // (reuses scr region after attn_sum2)
    const size_t ws_need_sc = 54 * MB + (size_t)NVTILE * 32 * 4096 * 2;  // 152 MB

    float* outp  = (float*)d_out;
    float* attnp = outp + (size_t)LQ * NBAT * DMOD;
    float* qb    = outp;

    const dim3 blk(256);
    const dim3 blk2(512);
    const size_t PSTRIDE = (size_t)LQ * NBAT * DMOD;
    const int NATTN = LQ * TKEY;

    if (ws_size < ws_need_old) {
        fill_zero_k<<<dim3((out_size + 255) / 256), blk, 0, stream>>>(outp, out_size);
        return;
    }

    if (ws_size >= ws_need_new) {
        // ======== fast path ========
        const bool useSC = (ws_size >= ws_need_sc);
        const int nCat = MEMLEN * NBAT * DMOD;
        const int nPos = TKEY * NBAT * DMOD;
        cvt3_bf16_k<<<dim3((2 * nCat + nPos) / 2048), blk, 0, stream>>>(
            memp, catc, nCat, x, catc + (size_t)nCat, nCat, pos, posc, nPos);
        tcvt3_k<<<dim3(1024), blk, 0, stream>>>(
            Wkv, wscr, Wrel, wscr + (size_t)2 * MB, Wq, wscr + (size_t)3 * MB);

        if (useSC) {
            // fused kv/r/q projections at 256^2 4-phase (224 blocks x 512 thr)
            proj3_256_k<<<dim3(224), blk2, 0, stream>>>(
                catc, wscr, kvb,
                posc, wscr + (size_t)2 * MB, rb,
                catc + (size_t)nCat, wscr + (size_t)3 * MB, qb);

            fill_zero_k<<<dim3((NATTN + 255) / 256), blk, 0, stream>>>(attnp, NATTN);
            flash_attn_k<true><<<dim3(LQ / 64, NBAT * NHEAD), blk, 0, stream>>>(
                qb, kvb, rb, ub, vb, m_arr, l_arr, vecb, scrh);
            attn_sum2_k<<<dim3(NVTILE, 2), blk, 0, stream>>>(scrh, m_arr, l_arr, attnp);

            // attn_out = vec @ Wo : 256^2 split-K=4 (scr region now dead -> part4)
            tcvt_bf16_k<<<dim3(DMOD / 64, HDIM / 64), blk, 0, stream>>>(Wo, wscr, HDIM, DMOD);
            mgemm256_k<4, false, float><<<dim3(DMOD / 256, LQ * NBAT / 256, 4), blk2, 0, stream>>>(
                vecb, wscr, nullptr, part4, LQ * NBAT, DMOD, HDIM);
            lnp_k<float, 4, false, bf16><<<dim3(LQ * NBAT), blk, 0, stream>>>(
                x, part4, PSTRIDE, nullptr, ln1g, ln1b, out1);
            // h1 = relu(out1 @ W1 + b1) : 256^2 (128 blocks)
            tcvt_bf16_k<<<dim3(DFFN / 64, DMOD / 64), blk, 0, stream>>>(W1, wscr, DMOD, DFFN);
            mgemm256_k<1, true, bf16><<<dim3(DFFN / 256, LQ * NBAT / 256, 1), blk2, 0, stream>>>(
                out1, wscr, b1, h1, LQ * NBAT, DFFN, DMOD);
            // ff = h1 @ W2 : 256^2 split-K=4
            tcvt_bf16_k<<<dim3(DMOD / 64, DFFN / 64), blk, 0, stream>>>(W2, wscr, DFFN, DMOD);
            mgemm256_k<4, false, float><<<dim3(DMOD / 256, LQ * NBAT / 256, 4), blk2, 0, stream>>>(
                h1, wscr, nullptr, part4, LQ * NBAT, DMOD, DFFN);
            lnp_k<bf16, 4, true, float><<<dim3(LQ * NBAT), blk, 0, stream>>>(
                out1, part4, PSTRIDE, b2, ln2g, ln2b, outp);
        } else {
            // mid-tier: round-7 verified structure (128^2 2-phase GEMMs)
            proj3_k<<<dim3(896), blk, 0, stream>>>(
                catc, wscr, kvb,
                posc, wscr + (size_t)2 * MB, rb,
                catc + (size_t)nCat, wscr + (size_t)3 * MB, qb);

            fill_zero_k<<<dim3((NATTN + 255) / 256), blk, 0, stream>>>(attnp, NATTN);
            flash_attn_k<false><<<dim3(LQ / 64, NBAT * NHEAD), blk, 0, stream>>>(
                qb, kvb, rb, ub, vb, m_arr, l_arr, vecb, nullptr);
            attn_mat4_k<<<dim3(NVTILE, 2), blk, 0, stream>>>(
                qb, kvb, rb, ub, vb, m_arr, l_arr, attnp);

            tcvt_bf16_k<<<dim3(DMOD / 64, HDIM / 64), blk, 0, stream>>>(Wo, wscr, HDIM, DMOD);
            mgemm128_k<2, false, float><<<dim3(DMOD / 128, LQ * NBAT / 128, 2), blk, 0, stream>>>(
                vecb, wscr, nullptr, part2, LQ * NBAT, DMOD, HDIM);
            lnp_k<float, 2, false, bf16><<<dim3(LQ * NBAT), blk, 0, stream>>>(
                x, part2, PSTRIDE, nullptr, ln1g, ln1b, out1);
            tcvt_bf16_k<<<dim3(DFFN / 64, DMOD / 64), blk, 0, stream>>>(W1, wscr, DMOD, DFFN);
            mgemm128_k<1, true, bf16><<<dim3(DFFN / 128, LQ * NBAT / 128, 1), blk, 0, stream>>>(
                out1, wscr, b1, h1, LQ * NBAT, DFFN, DMOD);
            tcvt_bf16_k<<<dim3(DMOD / 64, DFFN / 64), blk, 0, stream>>>(W2, wscr, DFFN, DMOD);
            mgemm128_k<2, false, float><<<dim3(DMOD / 128, LQ * NBAT / 128, 2), blk, 0, stream>>>(
                h1, wscr, nullptr, part2, LQ * NBAT, DMOD, DFFN);
            lnp_k<bf16, 2, true, float><<<dim3(LQ * NBAT), blk, 0, stream>>>(
                out1, part2, PSTRIDE, b2, ln2g, ln2b, outp);
        }
        return;
    }

    // ======== fallback path ========
    mgemm64_k<float, bf16, false><<<dim3(2 * HDIM / 64, TKEY * NBAT / 64), blk, 0, stream>>>(
        memp, x, MEMLEN * NBAT, Wkv, nullptr, kvb, TKEY * NBAT, 2 * HDIM, DMOD);
    mgemm64_k<float, bf16, false><<<dim3(HDIM / 64, TKEY * NBAT / 64), blk, 0, stream>>>(
        pos, pos, TKEY * NBAT, Wrel, nullptr, rb, TKEY * NBAT, HDIM, DMOD);
    mgemm64_k<float, float, false><<<dim3(HDIM / 64, LQ * NBAT / 64), blk, 0, stream>>>(
        x, x, LQ * NBAT, Wq, nullptr, qb, LQ * NBAT, HDIM, DMOD);

    fill_zero_k<<<dim3((NATTN + 255) / 256), blk, 0, stream>>>(attnp, NATTN);
    flash_attn_k<false><<<dim3(LQ / 64, NBAT * NHEAD), blk, 0, stream>>>(
        qb, kvb, rb, ub, vb, m_arr, l_arr, vecb, nullptr);
    attn_mat4_k<<<dim3(NVTILE, 2), blk, 0, stream>>>(
        qb, kvb, rb, ub, vb, m_arr, l_arr, attnp);

    mgemm64_k<bf16, bf16, false><<<dim3(DMOD / 64, LQ * NBAT / 64), blk, 0, stream>>>(
        vecb, vecb, LQ * NBAT, Wo, nullptr, aout, LQ * NBAT, DMOD, HDIM);
    ln_k<float, bf16, bf16><<<dim3(LQ * NBAT), blk, 0, stream>>>(x, aout, ln1g, ln1b, out1);
    mgemm64_k<bf16, bf16, true><<<dim3(DFFN / 64, LQ * NBAT / 64), blk, 0, stream>>>(
        out1, out1, LQ * NBAT, W1, b1, h1, LQ * NBAT, DFFN, DMOD);
    mgemm64_k<bf16, bf16, false><<<dim3(DMOD / 64, LQ * NBAT / 64), blk, 0, stream>>>(
        h1, h1, LQ * NBAT, W2, b2, f2o, LQ * NBAT, DMOD, DFFN);
    ln_k<bf16, bf16, float><<<dim3(LQ * NBAT), blk, 0, stream>>>(out1, f2o, ln2g, ln2b, outp);
}

// Round 10
// 447.043 us; speedup vs baseline: 1.0816x; 1.0816x over previous
//
#include <hip/hip_runtime.h>
#include <hip/hip_bf16.h>
#include <hip/hip_fp16.h>

using bf16 = __hip_bfloat16;

#define LQ      1024
#define NBAT    2
#define DMOD    1024
#define NHEAD   16
#define DHEAD   64
#define DFFN    4096
#define MEMLEN  1024
#define TKEY    2048
#define HDIM    1024
#define SCALE_F 0.125f
#define EPS_F   1e-5f
#define NVTILE  392   // total valid (i,j) tiles

typedef __attribute__((ext_vector_type(8))) short short8;
typedef __attribute__((ext_vector_type(4))) float f32x4;

__device__ __forceinline__ float ldf(const float* p) { return *p; }
__device__ __forceinline__ float ldf(const bf16* p) { return __bfloat162float(*p); }
__device__ __forceinline__ void stf(float* p, float v) { *p = v; }
__device__ __forceinline__ void stf(bf16* p, float v) { *p = __float2bfloat16(v); }

__device__ __forceinline__ void cpy4(bf16* dst, const float* src) {
    float4 w = *(const float4*)src;
    bf16 t[4] = {__float2bfloat16(w.x), __float2bfloat16(w.y),
                 __float2bfloat16(w.z), __float2bfloat16(w.w)};
    *(uint2*)dst = *(uint2*)t;
}
__device__ __forceinline__ void cpy4(bf16* dst, const bf16* src) {
    *(uint2*)dst = *(const uint2*)src;
}

// async global->LDS 16B: LDS dest MUST be wave-uniform; HW writes base + lane*16B
__device__ __forceinline__ void gload_lds16(const bf16* g, bf16* l) {
    __builtin_amdgcn_global_load_lds(
        (const __attribute__((address_space(1))) unsigned int*)g,
        (__attribute__((address_space(3))) unsigned int*)l, 16, 0, 0);
}

// T2 swizzle: logical (row, colE) -> LDS elem index (16B-granular XOR of row&7)
#define SWZ(row, colE) ((row) * 64 + ((colE) ^ (((row) & 7) << 3)))

// ---------------- fused fp32 -> bf16 elementwise converts (3 ranges, 1 launch) -------
__global__ __launch_bounds__(256)
void cvt3_bf16_k(const float* __restrict__ s0, bf16* __restrict__ d0, int n0,
                 const float* __restrict__ s1, bf16* __restrict__ d1, int n1,
                 const float* __restrict__ s2, bf16* __restrict__ d2, int n2)
{
    int i = (blockIdx.x * 256 + threadIdx.x) * 8;
    const float* s; bf16* d;
    if (i < n0)           { s = s0; d = d0; }
    else if (i < n0 + n1) { s = s1; d = d1; i -= n0; }
    else if (i < n0 + n1 + n2) { s = s2; d = d2; i -= n0 + n1; }
    else return;
    float4 v0 = *(const float4*)(s + i);
    float4 v1 = *(const float4*)(s + i + 4);
    bf16 t[8] = {__float2bfloat16(v0.x), __float2bfloat16(v0.y),
                 __float2bfloat16(v0.z), __float2bfloat16(v0.w),
                 __float2bfloat16(v1.x), __float2bfloat16(v1.y),
                 __float2bfloat16(v1.z), __float2bfloat16(v1.w)};
    *(uint4*)(d + i) = *(uint4*)t;
}

// ---------------- W [K][N] fp32 -> Wt [N][K] bf16, 64x64 tile body ----------------
__device__ __forceinline__ void tcvt_tile(const float* __restrict__ W,
                                          bf16* __restrict__ Wt,
                                          int K, int N, int n0, int k0, int tid,
                                          bf16 (*tile)[65])
{
    const int r = tid >> 2, cb = (tid & 3) * 16;
    #pragma unroll
    for (int e = 0; e < 16; e++)
        tile[r][cb + e] = __float2bfloat16(W[(size_t)(k0 + r) * N + n0 + cb + e]);
    __syncthreads();
    bf16 t[16];
    #pragma unroll
    for (int e = 0; e < 16; e++) t[e] = tile[cb + e][r];
    bf16* dst = Wt + (size_t)(n0 + r) * K + k0 + cb;
    *(uint4*)dst       = ((uint4*)t)[0];
    *(uint4*)(dst + 8) = ((uint4*)t)[1];
}

__global__ __launch_bounds__(256)
void tcvt_bf16_k(const float* __restrict__ W, bf16* __restrict__ Wt, int K, int N)
{
    __shared__ alignas(16) bf16 tile[64][65];
    tcvt_tile(W, Wt, K, N, blockIdx.x * 64, blockIdx.y * 64, threadIdx.x, tile);
}

// batched transpose-convert: Wkv(1024x2048) + Wrel(1024x1024) + Wq(1024x1024), K=1024
__global__ __launch_bounds__(256)
void tcvt3_k(const float* __restrict__ Wkv_, bf16* __restrict__ dkv,
             const float* __restrict__ Wrel_, bf16* __restrict__ dr,
             const float* __restrict__ Wq_, bf16* __restrict__ dq)
{
    __shared__ alignas(16) bf16 tile[64][65];
    int bid = blockIdx.x;
    const float* W; bf16* Wt; int N;
    if (bid < 512)      { W = Wkv_;  Wt = dkv; N = 2048; }
    else if (bid < 768) { W = Wrel_; Wt = dr;  N = 1024; bid -= 512; }
    else                { W = Wq_;   Wt = dq;  N = 1024; bid -= 768; }
    const int nb = N / 64;
    tcvt_tile(W, Wt, DMOD, N, (bid % nb) * 64, (bid / nb) * 64, threadIdx.x, tile);
}

// ---------------- 128x128 GEMM body (dbuf + T2 swizzle), verified 437.9us path ------
template<int SPLITS, bool RELU, typename TOUT>
__device__ __forceinline__ void gemm128_body(
    const bf16* __restrict__ A, const bf16* __restrict__ Bt,
    const float* __restrict__ bias, TOUT* __restrict__ Cbase,
    int M, int N, int K, int bx, int by, int bz,
    bf16* __restrict__ As, bf16* __restrict__ Bs)
{
    const int tid  = threadIdx.x;
    const int wave = tid >> 6, lane = tid & 63;
    const int m0 = by * 128, n0 = bx * 128;
    const int g = lane >> 4, c16 = lane & 15;
    const int wr = (wave >> 1) * 64, wc = (wave & 1) * 64;

    const int klen   = K / SPLITS;
    const int kstart = bz * klen;
    TOUT* C = Cbase + (size_t)bz * M * N;

    f32x4 acc[4][4];
    #pragma unroll
    for (int mi = 0; mi < 4; mi++)
        #pragma unroll
        for (int ni = 0; ni < 4; ni++) acc[mi][ni] = (f32x4)(0.f);

    const int r0 = (wave << 5) + (lane >> 3);
    const int cc = (((lane & 7) ^ (lane >> 3)) << 3);
    const bf16* agp = A  + (size_t)(m0 + r0) * K + kstart + cc;
    const bf16* bgp = Bt + (size_t)(n0 + r0) * K + kstart + cc;
    const int lb = wave * 2048;

    #pragma unroll
    for (int q = 0; q < 4; q++) {
        gload_lds16(agp + (size_t)(q * 8) * K, As + lb + q * 512);
        gload_lds16(bgp + (size_t)(q * 8) * K, Bs + lb + q * 512);
    }

    int cur = 0;
    for (int k0 = 0; k0 < klen; k0 += 64) {
        if (k0 + 64 < klen) {
            #pragma unroll
            for (int q = 0; q < 4; q++) {
                gload_lds16(agp + k0 + 64 + (size_t)(q * 8) * K,
                            As + (cur ^ 1) * 8192 + lb + q * 512);
                gload_lds16(bgp + k0 + 64 + (size_t)(q * 8) * K,
                            Bs + (cur ^ 1) * 8192 + lb + q * 512);
            }
            asm volatile("s_waitcnt vmcnt(8)" ::: "memory");
        } else {
            asm volatile("s_waitcnt vmcnt(0)" ::: "memory");
        }
        __builtin_amdgcn_s_barrier();
        short8 af[4][2], bfr[4][2];
        #pragma unroll
        for (int mi = 0; mi < 4; mi++) {
            const int row = wr + mi * 16 + c16;
            af[mi][0] = *(const short8*)&As[cur * 8192 + SWZ(row, g * 8)];
            af[mi][1] = *(const short8*)&As[cur * 8192 + SWZ(row, 32 + g * 8)];
        }
        #pragma unroll
        for (int ni = 0; ni < 4; ni++) {
            const int row = wc + ni * 16 + c16;
            bfr[ni][0] = *(const short8*)&Bs[cur * 8192 + SWZ(row, g * 8)];
            bfr[ni][1] = *(const short8*)&Bs[cur * 8192 + SWZ(row, 32 + g * 8)];
        }
        #pragma unroll
        for (int mi = 0; mi < 4; mi++)
            #pragma unroll
            for (int ni = 0; ni < 4; ni++) {
                acc[mi][ni] = __builtin_amdgcn_mfma_f32_16x16x32_bf16(
                                  af[mi][0], bfr[ni][0], acc[mi][ni], 0, 0, 0);
                acc[mi][ni] = __builtin_amdgcn_mfma_f32_16x16x32_bf16(
                                  af[mi][1], bfr[ni][1], acc[mi][ni], 0, 0, 0);
            }
        __builtin_amdgcn_s_barrier();
        cur ^= 1;
    }

    const int crow = g * 4;
    #pragma unroll
    for (int ni = 0; ni < 4; ni++) {
        const int n = n0 + wc + ni * 16 + c16;
        const float bv = (SPLITS == 1 && bias) ? bias[n] : 0.f;
        #pragma unroll
        for (int mi = 0; mi < 4; mi++) {
            #pragma unroll
            for (int reg = 0; reg < 4; reg++) {
                const int m = m0 + wr + mi * 16 + crow + reg;
                float v = acc[mi][ni][reg] + bv;
                if (RELU) v = fmaxf(v, 0.f);
                stf(C + (size_t)m * N + n, v);
            }
        }
    }
}

template<int SPLITS, bool RELU, typename TOUT>
__global__ __launch_bounds__(256)
void mgemm128_k(const bf16* __restrict__ A, const bf16* __restrict__ Bt,
                const float* __restrict__ bias, TOUT* __restrict__ Cbase,
                int M, int N, int K)
{
    __shared__ alignas(16) bf16 As[2 * 128 * 64];
    __shared__ alignas(16) bf16 Bs[2 * 128 * 64];
    gemm128_body<SPLITS, RELU, TOUT>(A, Bt, bias, Cbase, M, N, K,
                                     blockIdx.x, blockIdx.y, blockIdx.z, As, Bs);
}

// fused kv/r/q projections: one 896-block dispatch (512 kv + 256 r + 128 q)
__global__ __launch_bounds__(256)
void proj3_k(const bf16* __restrict__ catc, const bf16* __restrict__ wkvt,
             bf16* __restrict__ kvb,
             const bf16* __restrict__ posc, const bf16* __restrict__ wrelt,
             bf16* __restrict__ rb,
             const bf16* __restrict__ xb, const bf16* __restrict__ wqt,
             float* __restrict__ qb)
{
    __shared__ alignas(16) bf16 As[2 * 128 * 64];
    __shared__ alignas(16) bf16 Bs[2 * 128 * 64];
    int bid = blockIdx.x;
    if (bid < 512) {
        gemm128_body<1, false, bf16>(catc, wkvt, nullptr, kvb,
                                     TKEY * NBAT, 2 * HDIM, DMOD,
                                     bid & 15, bid >> 4, 0, As, Bs);
    } else if (bid < 768) {
        bid -= 512;
        gemm128_body<1, false, bf16>(posc, wrelt, nullptr, rb,
                                     TKEY * NBAT, HDIM, DMOD,
                                     bid & 7, bid >> 3, 0, As, Bs);
    } else {
        bid -= 768;
        gemm128_body<1, false, float>(xb, wqt, nullptr, qb,
                                      LQ * NBAT, HDIM, DMOD,
                                      bid & 7, bid >> 3, 0, As, Bs);
    }
}

// ---------------- MFMA GEMM, 64x64 tile (fallback path, fp32 weights) ----------------
template<typename TA, typename TOUT, bool RELU>
__global__ __launch_bounds__(256)
void mgemm64_k(const TA* __restrict__ A0, const TA* __restrict__ A1, int rowsplit,
               const float* __restrict__ Bw, const float* __restrict__ bias,
               TOUT* __restrict__ C, int M, int N, int K)
{
    __shared__ alignas(16) bf16 As[64][72];
    __shared__ alignas(16) bf16 Bs[64][72];
    const int tid  = threadIdx.x;
    const int m0   = blockIdx.y * 64;
    const int n0   = blockIdx.x * 64;
    const int wave = tid >> 6, lane = tid & 63;
    const int g = lane >> 4, c16 = lane & 15;

    f32x4 acc[4];
    #pragma unroll
    for (int nt = 0; nt < 4; nt++) acc[nt] = (f32x4)(0.f);

    const int ar = tid >> 2, akc = (tid & 3) * 16;
    const int grow = m0 + ar;
    const TA* Arow = (grow < rowsplit) ? (A0 + (size_t)grow * K)
                                       : (A1 + (size_t)(grow - rowsplit) * K);
    const int bn = tid & 63, bkb = (tid >> 6) * 16;
    const float* Bcol = Bw + n0 + bn;

    for (int k0 = 0; k0 < K; k0 += 64) {
        cpy4(&As[ar][akc],      Arow + k0 + akc);
        cpy4(&As[ar][akc + 4],  Arow + k0 + akc + 4);
        cpy4(&As[ar][akc + 8],  Arow + k0 + akc + 8);
        cpy4(&As[ar][akc + 12], Arow + k0 + akc + 12);
        {
            bf16 t16[16];
            #pragma unroll
            for (int e = 0; e < 16; e++)
                t16[e] = __float2bfloat16(Bcol[(size_t)(k0 + bkb + e) * N]);
            *(uint4*)&Bs[bn][bkb]     = *(uint4*)&t16[0];
            *(uint4*)&Bs[bn][bkb + 8] = *(uint4*)&t16[8];
        }
        __syncthreads();
        const short8 a0 = *(const short8*)&As[wave * 16 + c16][g * 8];
        const short8 a1 = *(const short8*)&As[wave * 16 + c16][32 + g * 8];
        #pragma unroll
        for (int nt = 0; nt < 4; nt++) {
            acc[nt] = __builtin_amdgcn_mfma_f32_16x16x32_bf16(
                          a0, *(const short8*)&Bs[nt * 16 + c16][g * 8], acc[nt], 0, 0, 0);
            acc[nt] = __builtin_amdgcn_mfma_f32_16x16x32_bf16(
                          a1, *(const short8*)&Bs[nt * 16 + c16][32 + g * 8], acc[nt], 0, 0, 0);
        }
        __syncthreads();
    }

    const int crow = (lane >> 4) * 4, ccol = lane & 15;
    #pragma unroll
    for (int nt = 0; nt < 4; nt++) {
        const int n = n0 + nt * 16 + ccol;
        const float bv = bias ? bias[n] : 0.f;
        #pragma unroll
        for (int rr = 0; rr < 4; rr++) {
            const int m = m0 + wave * 16 + crow + rr;
            float v = acc[nt][rr] + bv;
            if (RELU) v = fmaxf(v, 0.f);
            stf(C + (size_t)m * N + n, v);
        }
    }
}

union Frag8 { bf16 h[8]; short8 v; };

// ============ single-sweep online-softmax MFMA attention ============
// T14 async-STAGE split: next tile's K/R/V global loads issue into REGISTERS right
// after the score extraction (before softmax+PV, ~700 cyc of cover for L2/HBM
// latency); regs -> LDS write happens after the end-of-tile barrier. Same 2
// barriers/tile as before; +32 VGPR (LDS still binds occupancy at 2 blocks/CU).
template<bool WRSC>
__global__ __launch_bounds__(256)
void flash_attn_k(const float* __restrict__ q, const bf16* __restrict__ kv,
                  const bf16* __restrict__ rg, const float* __restrict__ ub,
                  const float* __restrict__ vb,
                  float* __restrict__ m_arr, float* __restrict__ l_arr,
                  bf16* __restrict__ vec, __half* __restrict__ scr)
{
    __shared__ alignas(16) bf16 Ks[64][72];
    __shared__ alignas(16) bf16 Rs[128][72];
    __shared__ alignas(16) bf16 Vt[64][72];
    __shared__ alignas(16) bf16 BDs[64][136];

    const int itile = (blockIdx.y < (NBAT * NHEAD / 2))
                          ? blockIdx.x : (gridDim.x - 1 - blockIdx.x);
    const int i0 = itile * 64;
    const int bh = blockIdx.y;
    const int b = bh >> 4, h = bh & 15;
    const int tid = threadIdx.x;
    const int wave = tid >> 6, lane = tid & 63;
    const int g = lane >> 4, c16 = lane & 15;
    const int dib = wave * 16 + g * 4;
    const int tbase = itile * 17 + itile * (itile - 1) / 2;

    // per-thread staging coordinates (fixed across tiles)
    const int krow = tid >> 2, kd = (tid & 3) * 16;
    const int rrow = tid >> 1, rd = (tid & 1) * 32;
    const int vj   = tid & 63, vd = (tid >> 6) * 16;

    uint4 kr[2], rr[4], vr[2];

    auto load_tile = [&](int t) {
        const int j0n = t * 64;
        const int jj0n = j0n + (LQ - 64) - i0;
        {
            const bf16* src = kv + ((size_t)(j0n + krow) * NBAT + b) * (2 * HDIM)
                                 + h * DHEAD + kd;
            kr[0] = *(const uint4*)src;
            kr[1] = *(const uint4*)(src + 8);
        }
        {
            const int jj = jj0n + rrow;
            if (jj < TKEY) {
                const bf16* src = rg + ((size_t)jj * NBAT + b) * HDIM + h * DHEAD + rd;
                #pragma unroll
                for (int u = 0; u < 4; u++) rr[u] = *(const uint4*)(src + u * 8);
            } else {
                const uint4 z = make_uint4(0, 0, 0, 0);
                #pragma unroll
                for (int u = 0; u < 4; u++) rr[u] = z;
            }
        }
        {
            const bf16* src = kv + ((size_t)(j0n + vj) * NBAT + b) * (2 * HDIM)
                                 + HDIM + h * DHEAD + vd;
            vr[0] = *(const uint4*)src;
            vr[1] = *(const uint4*)(src + 8);
        }
    };
    auto write_tile = [&]() {
        *(uint4*)&Ks[krow][kd]     = kr[0];
        *(uint4*)&Ks[krow][kd + 8] = kr[1];
        #pragma unroll
        for (int u = 0; u < 4; u++) *(uint4*)&Rs[rrow][rd + u * 8] = rr[u];
        bf16 tmp[16];
        *(uint4*)&tmp[0] = vr[0];
        *(uint4*)&tmp[8] = vr[1];
        #pragma unroll
        for (int e = 0; e < 16; e++) Vt[vd + e][vj] = tmp[e];
    };

    Frag8 fu0, fu1, fv0, fv1;
    {
        const float* qrow = q + ((size_t)(i0 + wave * 16 + c16) * NBAT + b) * HDIM + h * DHEAD;
        const float* ubp = ub + h * DHEAD;
        const float* vbp = vb + h * DHEAD;
        #pragma unroll
        for (int e = 0; e < 8; e++) {
            float q0 = qrow[g * 8 + e], q1 = qrow[32 + g * 8 + e];
            fu0.h[e] = __float2bfloat16(q0 + ubp[g * 8 + e]);
            fu1.h[e] = __float2bfloat16(q1 + ubp[32 + g * 8 + e]);
            fv0.h[e] = __float2bfloat16(q0 + vbp[g * 8 + e]);
            fv1.h[e] = __float2bfloat16(q1 + vbp[32 + g * 8 + e]);
        }
    }

    float mrow[4] = {-3e38f, -3e38f, -3e38f, -3e38f};
    float lrow[4] = {0.f, 0.f, 0.f, 0.f};
    f32x4 Oacc[4];
    #pragma unroll
    for (int nt = 0; nt < 4; nt++) Oacc[nt] = (f32x4)(0.f);

    const int ntiles = i0 / 64 + 17;

    // prologue: stage tile 0 directly
    load_tile(0);
    write_tile();
    __syncthreads();

    for (int t = 0; t < ntiles; t++) {
        const int j0 = t * 64;
        __half* scp = nullptr;
        if (WRSC) scp = scr + ((size_t)bh * NVTILE + tbase + t) * 4096;
        // ---- QK^T (AC) ----
        f32x4 ac[4];
        #pragma unroll
        for (int nt = 0; nt < 4; nt++) {
            ac[nt] = (f32x4)(0.f);
            ac[nt] = __builtin_amdgcn_mfma_f32_16x16x32_bf16(
                         fu0.v, *(const short8*)&Ks[nt * 16 + c16][g * 8], ac[nt], 0, 0, 0);
            ac[nt] = __builtin_amdgcn_mfma_f32_16x16x32_bf16(
                         fu1.v, *(const short8*)&Ks[nt * 16 + c16][32 + g * 8], ac[nt], 0, 0, 0);
        }
        // ---- BD (rel) -> BDs stripe (intra-wave round-trip) ----
        #pragma unroll
        for (int nt = 0; nt < 8; nt++) {
            f32x4 bd = (f32x4)(0.f);
            bd = __builtin_amdgcn_mfma_f32_16x16x32_bf16(
                     fv0.v, *(const short8*)&Rs[nt * 16 + c16][g * 8], bd, 0, 0, 0);
            bd = __builtin_amdgcn_mfma_f32_16x16x32_bf16(
                     fv1.v, *(const short8*)&Rs[nt * 16 + c16][32 + g * 8], bd, 0, 0, 0);
            #pragma unroll
            for (int reg = 0; reg < 4; reg++)
                BDs[dib + reg][nt * 16 + c16] = __float2bfloat16(bd[reg]);
        }
        // ---- scores (+ packed fp16 cache) ----
        float sv[4][4];
        #pragma unroll
        for (int reg = 0; reg < 4; reg++) {
            const int di = dib + reg;
            const int colbase = 63 - di;
            __half hv[4];
            #pragma unroll
            for (int nt = 0; nt < 4; nt++) {
                const int dj = nt * 16 + c16;
                float s = (ac[nt][reg] +
                           __bfloat162float(BDs[di][colbase + dj])) * SCALE_F;
                if (j0 + dj > i0 + di + MEMLEN) s = -1e30f;
                sv[nt][reg] = s;
                if (WRSC) hv[nt] = __float2half(s);
            }
            if (WRSC) *(uint2*)&scp[di * 64 + c16 * 4] = *(uint2*)hv;
        }
        // ---- T14: issue next tile's global loads now (cover = softmax + PV) ----
        if (t + 1 < ntiles) load_tile(t + 1);
        // ---- online softmax ----
        #pragma unroll
        for (int reg = 0; reg < 4; reg++) {
            float tm = fmaxf(fmaxf(sv[0][reg], sv[1][reg]),
                             fmaxf(sv[2][reg], sv[3][reg]));
            #pragma unroll
            for (int mk = 1; mk < 16; mk <<= 1)
                tm = fmaxf(tm, __shfl_xor(tm, mk));
            const float nm = fmaxf(mrow[reg], tm);
            const float alpha = __expf(mrow[reg] - nm);
            float ev[4];
            #pragma unroll
            for (int nt = 0; nt < 4; nt++) ev[nt] = __expf(sv[nt][reg] - nm);
            float ps = ev[0] + ev[1] + ev[2] + ev[3];
            #pragma unroll
            for (int mk = 1; mk < 16; mk <<= 1)
                ps += __shfl_xor(ps, mk);
            lrow[reg] = lrow[reg] * alpha + ps;
            mrow[reg] = nm;
            #pragma unroll
            for (int nt = 0; nt < 4; nt++) {
                Oacc[nt][reg] *= alpha;
                BDs[dib + reg][nt * 16 + c16] = __float2bfloat16(ev[nt]);
            }
        }
        // ---- PV ----
        short8 p0 = *(const short8*)&BDs[wave * 16 + c16][g * 8];
        short8 p1 = *(const short8*)&BDs[wave * 16 + c16][32 + g * 8];
        #pragma unroll
        for (int nt = 0; nt < 4; nt++) {
            Oacc[nt] = __builtin_amdgcn_mfma_f32_16x16x32_bf16(
                           p0, *(const short8*)&Vt[nt * 16 + c16][g * 8], Oacc[nt], 0, 0, 0);
            Oacc[nt] = __builtin_amdgcn_mfma_f32_16x16x32_bf16(
                           p1, *(const short8*)&Vt[nt * 16 + c16][32 + g * 8], Oacc[nt], 0, 0, 0);
        }
        __syncthreads();                // all reads of tile t's K/R/V/BDs done
        if (t + 1 < ntiles) {
            write_tile();               // regs (landed loads) -> LDS
            __syncthreads();            // staging visible to all waves
        }
    }

    float invl[4];
    #pragma unroll
    for (int reg = 0; reg < 4; reg++) invl[reg] = 1.f / lrow[reg];
    #pragma unroll
    for (int nt = 0; nt < 4; nt++)
        #pragma unroll
        for (int reg = 0; reg < 4; reg++)
            vec[((size_t)(i0 + dib + reg) * NBAT + b) * HDIM + h * DHEAD + nt * 16 + c16]
                = __float2bfloat16(Oacc[nt][reg] * invl[reg]);
    if (c16 == 0) {
        #pragma unroll
        for (int reg = 0; reg < 4; reg++) {
            const int idx = ((i0 + dib + reg) * NBAT + b) * NHEAD + h;
            m_arr[idx] = mrow[reg];
            l_arr[idx] = lrow[reg];
        }
    }
}

// ============ attn matrix from cached scores — no atomics, self-zeroing ==========
// grid (512, 2): bx = it*32 + jt covers ALL tiles; invalid tiles write zeros
// directly (drops the separate fill_zero pass). y = row-half.
__global__ __launch_bounds__(256)
void attn_sum2_k(const __half* __restrict__ scr, const float* __restrict__ m_arr,
                 const float* __restrict__ l_arr, float* __restrict__ attn)
{
    const int it = blockIdx.x >> 5, jt = blockIdx.x & 31;
    const int i0 = it * 64, j0 = jt * 64;
    const int tid = threadIdx.x;
    const int row = blockIdx.y * 32 + (tid >> 3);
    const int pb = (tid & 7) * 8;
    const int i = i0 + row;

    if (jt > it + 16) {     // fully-masked tile
        #pragma unroll
        for (int e = 0; e < 8; e++) {
            const int p = pb + e;
            const int j = (p & 3) * 16 + (p >> 2);
            attn[(size_t)i * TKEY + j0 + j] = 0.f;
        }
        return;
    }
    const int ft = it * 17 + it * (it - 1) / 2 + jt;   // flat valid-tile index

    float acc[8] = {0.f, 0.f, 0.f, 0.f, 0.f, 0.f, 0.f, 0.f};
    for (int bh = 0; bh < NBAT * NHEAD; bh++) {
        const int b = bh >> 4, h = bh & 15;
        const __half* sp = scr + ((size_t)bh * NVTILE + ft) * 4096 + row * 64 + pb;
        const int idx = (i * NBAT + b) * NHEAD + h;
        const float mi = m_arr[idx];
        const float il = 1.f / l_arr[idx];
        union { uint4 v; __half hx[8]; } u;
        u.v = *(const uint4*)sp;
        #pragma unroll
        for (int e = 0; e < 8; e++)
            acc[e] += __expf(__half2float(u.hx[e]) - mi) * il;
    }
    const float inv = 1.f / (NBAT * NHEAD);
    #pragma unroll
    for (int e = 0; e < 8; e++) {
        const int p = pb + e;
        const int j = (p & 3) * 16 + (p >> 2);
        attn[(size_t)i * TKEY + j0 + j] = acc[e] * inv;
    }
}

// ============ attn matrix via MFMA (mid-tier fallback; atomic-accumulating) ==========
__global__ __launch_bounds__(256)
void attn_mat4_k(const float* __restrict__ q, const bf16* __restrict__ kv,
                 const bf16* __restrict__ rg, const float* __restrict__ ub,
                 const float* __restrict__ vb, const float* __restrict__ m_arr,
                 const float* __restrict__ l_arr, float* __restrict__ attn)
{
    int f = blockIdx.x, it = 0, base = 0;
    for (it = 0; it < 16; it++) {
        const int cnt = it + 17;
        if (f < base + cnt) break;
        base += cnt;
    }
    const int i0 = it * 64;
    const int j0 = (f - base) * 64;
    const int bhb = blockIdx.y * 16;

    __shared__ alignas(16) bf16 Ks[64][72];
    __shared__ alignas(16) bf16 Rs[128][72];
    __shared__ alignas(16) bf16 BDs[64][136];
    const int tid = threadIdx.x;
    const int wave = tid >> 6, lane = tid & 63;
    const int g = lane >> 4, c16 = lane & 15;
    const int dib = wave * 16 + g * 4;
    const int jj0 = j0 + (LQ - 64) - i0;
    float psum[4][4] = {};

    for (int bh = bhb; bh < bhb + 16; bh++) {
        const int b = bh >> 4, h = bh & 15;
        Frag8 fu0, fu1, fv0, fv1;
        {
            const float* qrow = q + ((size_t)(i0 + wave * 16 + c16) * NBAT + b) * HDIM + h * DHEAD;
            const float* ubp = ub + h * DHEAD;
            const float* vbp = vb + h * DHEAD;
            #pragma unroll
            for (int e = 0; e < 8; e++) {
                float q0 = qrow[g * 8 + e], q1 = qrow[32 + g * 8 + e];
                fu0.h[e] = __float2bfloat16(q0 + ubp[g * 8 + e]);
                fu1.h[e] = __float2bfloat16(q1 + ubp[32 + g * 8 + e]);
                fv0.h[e] = __float2bfloat16(q0 + vbp[g * 8 + e]);
                fv1.h[e] = __float2bfloat16(q1 + vbp[32 + g * 8 + e]);
            }
        }
        {
            const int row = tid >> 2, dbase = (tid & 3) * 16;
            const bf16* src = kv + ((size_t)(j0 + row) * NBAT + b) * (2 * HDIM)
                                 + h * DHEAD + dbase;
            *(uint4*)&Ks[row][dbase]     = *(const uint4*)src;
            *(uint4*)&Ks[row][dbase + 8] = *(const uint4*)(src + 8);
        }
        {
            const int row = tid >> 1, dbase = (tid & 1) * 32;
            const int jj = jj0 + row;
            if (jj < TKEY) {
                const bf16* src = rg + ((size_t)jj * NBAT + b) * HDIM + h * DHEAD + dbase;
                #pragma unroll
                for (int u = 0; u < 4; u++)
                    *(uint4*)&Rs[row][dbase + u * 8] = *(const uint4*)(src + u * 8);
            } else {
                const uint4 z = make_uint4(0, 0, 0, 0);
                #pragma unroll
                for (int u = 0; u < 4; u++)
                    *(uint4*)&Rs[row][dbase + u * 8] = z;
            }
        }
        __syncthreads();
        f32x4 ac[4];
        #pragma unroll
        for (int nt = 0; nt < 4; nt++) {
            ac[nt] = (f32x4)(0.f);
            ac[nt] = __builtin_amdgcn_mfma_f32_16x16x32_bf16(
                         fu0.v, *(const short8*)&Ks[nt * 16 + c16][g * 8], ac[nt], 0, 0, 0);
            ac[nt] = __builtin_amdgcn_mfma_f32_16x16x32_bf16(
                         fu1.v, *(const short8*)&Ks[nt * 16 + c16][32 + g * 8], ac[nt], 0, 0, 0);
        }
        #pragma unroll
        for (int nt = 0; nt < 8; nt++) {
            f32x4 bd = (f32x4)(0.f);
            bd = __builtin_amdgcn_mfma_f32_16x16x32_bf16(
                     fv0.v, *(const short8*)&Rs[nt * 16 + c16][g * 8], bd, 0, 0, 0);
            bd = __builtin_amdgcn_mfma_f32_16x16x32_bf16(
                     fv1.v, *(const short8*)&Rs[nt * 16 + c16][32 + g * 8], bd, 0, 0, 0);
            #pragma unroll
            for (int reg = 0; reg < 4; reg++)
                BDs[dib + reg][nt * 16 + c16] = __float2bfloat16(bd[reg]);
        }
        #pragma unroll
        for (int reg = 0; reg < 4; reg++) {
            const int di = dib + reg;
            const int colbase = 63 - di;
            const int idx = ((i0 + di) * NBAT + b) * NHEAD + h;
            const float mi = m_arr[idx];
            const float il = 1.f / l_arr[idx];
            #pragma unroll
            for (int nt = 0; nt < 4; nt++) {
                const int dj = nt * 16 + c16;
                float s = (ac[nt][reg] +
                           __bfloat162float(BDs[di][colbase + dj])) * SCALE_F;
                float p = (j0 + dj > i0 + di + MEMLEN) ? 0.f : __expf(s - mi) * il;
                psum[nt][reg] += p;
            }
        }
        __syncthreads();
    }
    const float inv = 1.f / (NBAT * NHEAD);
    #pragma unroll
    for (int nt = 0; nt < 4; nt++)
        #pragma unroll
        for (int reg = 0; reg < 4; reg++)
            atomicAdd(&attn[(size_t)(i0 + dib + reg) * TKEY + j0 + nt * 16 + c16],
                      psum[nt][reg] * inv);
}

// ---------------- fused residual + LayerNorm ----------------
template<typename T1, typename T2, typename TOUT>
__global__ __launch_bounds__(256)
void ln_k(const T1* __restrict__ a, const T2* __restrict__ c,
          const float* __restrict__ g, const float* __restrict__ bb,
          TOUT* __restrict__ out)
{
    const int row = blockIdx.x;
    const int tid = threadIdx.x;
    const size_t base = (size_t)row * DMOD;
    float vals[4];
    float s = 0.f, sq = 0.f;
    #pragma unroll
    for (int t = 0; t < 4; t++) {
        const int dcol = tid + t * 256;
        float v = ldf(a + base + dcol) + ldf(c + base + dcol);
        vals[t] = v; s += v; sq += v * v;
    }
    __shared__ float rs[256], rq[256];
    rs[tid] = s; rq[tid] = sq;
    __syncthreads();
    for (int st = 128; st > 0; st >>= 1) {
        if (tid < st) { rs[tid] += rs[tid + st]; rq[tid] += rq[tid + st]; }
        __syncthreads();
    }
    const float mean = rs[0] / DMOD;
    const float var = rq[0] / DMOD - mean * mean;
    const float rstd = rsqrtf(fmaxf(var, 0.f) + EPS_F);
    #pragma unroll
    for (int t = 0; t < 4; t++) {
        const int dcol = tid + t * 256;
        float v = (vals[t] - mean) * rstd * g[dcol] + bb[dcol];
        stf(out + base + dcol, v);
    }
}

// ---------------- residual + NP split-K fp32 partials (+optional bias) + LayerNorm ----
template<typename TA, int NP, bool HASB, typename TOUT>
__global__ __launch_bounds__(256)
void lnp_k(const TA* __restrict__ a, const float* __restrict__ part, size_t pstride,
           const float* __restrict__ biasvec, const float* __restrict__ g,
           const float* __restrict__ bb, TOUT* __restrict__ out)
{
    const int row = blockIdx.x;
    const int tid = threadIdx.x;
    const size_t base = (size_t)row * DMOD;
    float vals[4];
    float s = 0.f, sq = 0.f;
    #pragma unroll
    for (int t = 0; t < 4; t++) {
        const int dcol = tid + t * 256;
        float v = ldf(a + base + dcol);
        #pragma unroll
        for (int p = 0; p < NP; p++) v += part[(size_t)p * pstride + base + dcol];
        if (HASB) v += biasvec[dcol];
        vals[t] = v; s += v; sq += v * v;
    }
    __shared__ float rs[256], rq[256];
    rs[tid] = s; rq[tid] = sq;
    __syncthreads();
    for (int st = 128; st > 0; st >>= 1) {
        if (tid < st) { rs[tid] += rs[tid + st]; rq[tid] += rq[tid + st]; }
        __syncthreads();
    }
    const float mean = rs[0] / DMOD;
    const float var = rq[0] / DMOD - mean * mean;
    const float rstd = rsqrtf(fmaxf(var, 0.f) + EPS_F);
    #pragma unroll
    for (int t = 0; t < 4; t++) {
        const int dcol = tid + t * 256;
        float v = (vals[t] - mean) * rstd * g[dcol] + bb[dcol];
        stf(out + base + dcol, v);
    }
}

__global__ void fill_zero_k(float* __restrict__ p, int n) {
    int i = blockIdx.x * 256 + threadIdx.x;
    if (i < n) p[i] = 0.f;
}

extern "C" void kernel_launch(void* const* d_in, const int* in_sizes, int n_in,
                              void* d_out, int out_size, void* d_ws, size_t ws_size,
                              hipStream_t stream)
{
    const float* x    = (const float*)d_in[0];
    const float* pos  = (const float*)d_in[1];
    const float* ub   = (const float*)d_in[2];
    const float* vb   = (const float*)d_in[3];
    const float* memp = (const float*)d_in[4];
    const float* Wq   = (const float*)d_in[5];
    const float* Wkv  = (const float*)d_in[6];
    const float* Wo   = (const float*)d_in[7];
    const float* Wrel = (const float*)d_in[8];
    const float* ln1g = (const float*)d_in[9];
    const float* ln1b = (const float*)d_in[10];
    const float* W1   = (const float*)d_in[11];
    const float* b1   = (const float*)d_in[12];
    const float* W2   = (const float*)d_in[13];
    const float* b2   = (const float*)d_in[14];
    const float* ln2g = (const float*)d_in[15];
    const float* ln2b = (const float*)d_in[16];

    // ---- workspace, lifetime-aliased ----
    char* wsb = (char*)d_ws;
    const size_t MB = 1048576;
    bf16*  kvb   = (bf16*)(wsb + 0);
    bf16*  h1    = (bf16*)(wsb + 0);
    bf16*  rb    = (bf16*)(wsb + 16 * MB);
    bf16*  aout  = (bf16*)(wsb + 16 * MB);
    bf16*  f2o   = (bf16*)(wsb + 16 * MB);
    bf16*  out1  = (bf16*)(wsb + 20 * MB);
    bf16*  vecb  = (bf16*)(wsb + 24 * MB);
    float* m_arr = (float*)(wsb + 28 * MB);
    float* l_arr = (float*)(wsb + 28 * MB + 131072);
    const size_t ws_need_old = 28 * MB + 262144;
    bf16*  catc  = (bf16*)(wsb + 30 * MB);
    bf16*  posc  = (bf16*)(wsb + 38 * MB);
    float* part2 = (float*)(wsb + 30 * MB);
    bf16*  wscr  = (bf16*)(wsb + 46 * MB);
    const size_t ws_need_new = 54 * MB;
    __half* scrh = (__half*)(wsb + 54 * MB);   // fp16 score cache, 98 MB
    const size_t ws_need_sc = 54 * MB + (size_t)NVTILE * 32 * 4096 * 2;  // 152 MB

    float* outp  = (float*)d_out;
    float* attnp = outp + (size_t)LQ * NBAT * DMOD;
    float* qb    = outp;

    const dim3 blk(256);
    const size_t PSTRIDE = (size_t)LQ * NBAT * DMOD;
    const int NATTN = LQ * TKEY;

    if (ws_size < ws_need_old) {
        fill_zero_k<<<dim3((out_size + 255) / 256), blk, 0, stream>>>(outp, out_size);
        return;
    }

    if (ws_size >= ws_need_new) {
        // ======== fast path (verified 128^2 GEMM structure + T14 flash) ========
        const bool useSC = (ws_size >= ws_need_sc);
        const int nCat = MEMLEN * NBAT * DMOD;
        const int nPos = TKEY * NBAT * DMOD;
        cvt3_bf16_k<<<dim3((2 * nCat + nPos) / 2048), blk, 0, stream>>>(
            memp, catc, nCat, x, catc + (size_t)nCat, nCat, pos, posc, nPos);
        tcvt3_k<<<dim3(1024), blk, 0, stream>>>(
            Wkv, wscr, Wrel, wscr + (size_t)2 * MB, Wq, wscr + (size_t)3 * MB);

        proj3_k<<<dim3(896), blk, 0, stream>>>(
            catc, wscr, kvb,
            posc, wscr + (size_t)2 * MB, rb,
            catc + (size_t)nCat, wscr + (size_t)3 * MB, qb);

        if (useSC) {
            flash_attn_k<true><<<dim3(LQ / 64, NBAT * NHEAD), blk, 0, stream>>>(
                qb, kvb, rb, ub, vb, m_arr, l_arr, vecb, scrh);
            attn_sum2_k<<<dim3(512, 2), blk, 0, stream>>>(scrh, m_arr, l_arr, attnp);
        } else {
            fill_zero_k<<<dim3((NATTN + 255) / 256), blk, 0, stream>>>(attnp, NATTN);
            flash_attn_k<false><<<dim3(LQ / 64, NBAT * NHEAD), blk, 0, stream>>>(
                qb, kvb, rb, ub, vb, m_arr, l_arr, vecb, nullptr);
            attn_mat4_k<<<dim3(NVTILE, 2), blk, 0, stream>>>(
                qb, kvb, rb, ub, vb, m_arr, l_arr, attnp);
        }

        tcvt_bf16_k<<<dim3(DMOD / 64, HDIM / 64), blk, 0, stream>>>(Wo, wscr, HDIM, DMOD);
        mgemm128_k<2, false, float><<<dim3(DMOD / 128, LQ * NBAT / 128, 2), blk, 0, stream>>>(
            vecb, wscr, nullptr, part2, LQ * NBAT, DMOD, HDIM);
        lnp_k<float, 2, false, bf16><<<dim3(LQ * NBAT), blk, 0, stream>>>(
            x, part2, PSTRIDE, nullptr, ln1g, ln1b, out1);
        tcvt_bf16_k<<<dim3(DFFN / 64, DMOD / 64), blk, 0, stream>>>(W1, wscr, DMOD, DFFN);
        mgemm128_k<1, true, bf16><<<dim3(DFFN / 128, LQ * NBAT / 128, 1), blk, 0, stream>>>(
            out1, wscr, b1, h1, LQ * NBAT, DFFN, DMOD);
        tcvt_bf16_k<<<dim3(DMOD / 64, DFFN / 64), blk, 0, stream>>>(W2, wscr, DFFN, DMOD);
        mgemm128_k<2, false, float><<<dim3(DMOD / 128, LQ * NBAT / 128, 2), blk, 0, stream>>>(
            h1, wscr, nullptr, part2, LQ * NBAT, DMOD, DFFN);
        lnp_k<bf16, 2, true, float><<<dim3(LQ * NBAT), blk, 0, stream>>>(
            out1, part2, PSTRIDE, b2, ln2g, ln2b, outp);
        return;
    }

    // ======== fallback path ========
    mgemm64_k<float, bf16, false><<<dim3(2 * HDIM / 64, TKEY * NBAT / 64), blk, 0, stream>>>(
        memp, x, MEMLEN * NBAT, Wkv, nullptr, kvb, TKEY * NBAT, 2 * HDIM, DMOD);
    mgemm64_k<float, bf16, false><<<dim3(HDIM / 64, TKEY * NBAT / 64), blk, 0, stream>>>(
        pos, pos, TKEY * NBAT, Wrel, nullptr, rb, TKEY * NBAT, HDIM, DMOD);
    mgemm64_k<float, float, false><<<dim3(HDIM / 64, LQ * NBAT / 64), blk, 0, stream>>>(
        x, x, LQ * NBAT, Wq, nullptr, qb, LQ * NBAT, HDIM, DMOD);

    fill_zero_k<<<dim3((NATTN + 255) / 256), blk, 0, stream>>>(attnp, NATTN);
    flash_attn_k<false><<<dim3(LQ / 64, NBAT * NHEAD), blk, 0, stream>>>(
        qb, kvb, rb, ub, vb, m_arr, l_arr, vecb, nullptr);
    attn_mat4_k<<<dim3(NVTILE, 2), blk, 0, stream>>>(
        qb, kvb, rb, ub, vb, m_arr, l_arr, attnp);

    mgemm64_k<bf16, bf16, false><<<dim3(DMOD / 64, LQ * NBAT / 64), blk, 0, stream>>>(
        vecb, vecb, LQ * NBAT, Wo, nullptr, aout, LQ * NBAT, DMOD, HDIM);
    ln_k<float, bf16, bf16><<<dim3(LQ * NBAT), blk, 0, stream>>>(x, aout, ln1g, ln1b, out1);
    mgemm64_k<bf16, bf16, true><<<dim3(DFFN / 64, LQ * NBAT / 64), blk, 0, stream>>>(
        out1, out1, LQ * NBAT, W1, b1, h1, LQ * NBAT, DFFN, DMOD);
    mgemm64_k<bf16, bf16, false><<<dim3(DMOD / 64, LQ * NBAT / 64), blk, 0, stream>>>(
        h1, h1, LQ * NBAT, W2, b2, f2o, LQ * NBAT, DMOD, DFFN);
    ln_k<bf16, bf16, float><<<dim3(LQ * NBAT), blk, 0, stream>>>(out1, f2o, ln2g, ln2b, outp);
}

// Round 11
// 434.086 us; speedup vs baseline: 1.1139x; 1.0299x over previous
//
#include <hip/hip_runtime.h>
#include <hip/hip_bf16.h>
#include <hip/hip_fp16.h>

using bf16 = __hip_bfloat16;

#define LQ      1024
#define NBAT    2
#define DMOD    1024
#define NHEAD   16
#define DHEAD   64
#define DFFN    4096
#define MEMLEN  1024
#define TKEY    2048
#define HDIM    1024
#define SCALE_F 0.125f
#define EPS_F   1e-5f
#define NVTILE  392   // total valid (i,j) tiles

typedef __attribute__((ext_vector_type(8))) short short8;
typedef __attribute__((ext_vector_type(4))) float f32x4;

__device__ __forceinline__ float ldf(const float* p) { return *p; }
__device__ __forceinline__ float ldf(const bf16* p) { return __bfloat162float(*p); }
__device__ __forceinline__ void stf(float* p, float v) { *p = v; }
__device__ __forceinline__ void stf(bf16* p, float v) { *p = __float2bfloat16(v); }

__device__ __forceinline__ void cpy4(bf16* dst, const float* src) {
    float4 w = *(const float4*)src;
    bf16 t[4] = {__float2bfloat16(w.x), __float2bfloat16(w.y),
                 __float2bfloat16(w.z), __float2bfloat16(w.w)};
    *(uint2*)dst = *(uint2*)t;
}
__device__ __forceinline__ void cpy4(bf16* dst, const bf16* src) {
    *(uint2*)dst = *(const uint2*)src;
}

// async global->LDS 16B: LDS dest MUST be wave-uniform; HW writes base + lane*16B
__device__ __forceinline__ void gload_lds16(const bf16* g, bf16* l) {
    __builtin_amdgcn_global_load_lds(
        (const __attribute__((address_space(1))) unsigned int*)g,
        (__attribute__((address_space(3))) unsigned int*)l, 16, 0, 0);
}

// T2 swizzle: logical (row, colE) -> LDS elem index (16B-granular XOR of row&7)
#define SWZ(row, colE) ((row) * 64 + ((colE) ^ (((row) & 7) << 3)))

// ---------------- fused fp32 -> bf16 elementwise converts (3 ranges, 1 launch) -------
__global__ __launch_bounds__(256)
void cvt3_bf16_k(const float* __restrict__ s0, bf16* __restrict__ d0, int n0,
                 const float* __restrict__ s1, bf16* __restrict__ d1, int n1,
                 const float* __restrict__ s2, bf16* __restrict__ d2, int n2)
{
    int i = (blockIdx.x * 256 + threadIdx.x) * 8;
    const float* s; bf16* d;
    if (i < n0)           { s = s0; d = d0; }
    else if (i < n0 + n1) { s = s1; d = d1; i -= n0; }
    else if (i < n0 + n1 + n2) { s = s2; d = d2; i -= n0 + n1; }
    else return;
    float4 v0 = *(const float4*)(s + i);
    float4 v1 = *(const float4*)(s + i + 4);
    bf16 t[8] = {__float2bfloat16(v0.x), __float2bfloat16(v0.y),
                 __float2bfloat16(v0.z), __float2bfloat16(v0.w),
                 __float2bfloat16(v1.x), __float2bfloat16(v1.y),
                 __float2bfloat16(v1.z), __float2bfloat16(v1.w)};
    *(uint4*)(d + i) = *(uint4*)t;
}

// ---------------- W [K][N] fp32 -> Wt [N][K] bf16, 64x64 tile body ----------------
__device__ __forceinline__ void tcvt_tile(const float* __restrict__ W,
                                          bf16* __restrict__ Wt,
                                          int K, int N, int n0, int k0, int tid,
                                          bf16 (*tile)[65])
{
    const int r = tid >> 2, cb = (tid & 3) * 16;
    #pragma unroll
    for (int e = 0; e < 16; e++)
        tile[r][cb + e] = __float2bfloat16(W[(size_t)(k0 + r) * N + n0 + cb + e]);
    __syncthreads();
    bf16 t[16];
    #pragma unroll
    for (int e = 0; e < 16; e++) t[e] = tile[cb + e][r];
    bf16* dst = Wt + (size_t)(n0 + r) * K + k0 + cb;
    *(uint4*)dst       = ((uint4*)t)[0];
    *(uint4*)(dst + 8) = ((uint4*)t)[1];
}

__global__ __launch_bounds__(256)
void tcvt_bf16_k(const float* __restrict__ W, bf16* __restrict__ Wt, int K, int N)
{
    __shared__ alignas(16) bf16 tile[64][65];
    tcvt_tile(W, Wt, K, N, blockIdx.x * 64, blockIdx.y * 64, threadIdx.x, tile);
}

// batched transpose-convert: Wkv(1024x2048) + Wrel(1024x1024) + Wq(1024x1024), K=1024
__global__ __launch_bounds__(256)
void tcvt3_k(const float* __restrict__ Wkv_, bf16* __restrict__ dkv,
             const float* __restrict__ Wrel_, bf16* __restrict__ dr,
             const float* __restrict__ Wq_, bf16* __restrict__ dq)
{
    __shared__ alignas(16) bf16 tile[64][65];
    int bid = blockIdx.x;
    const float* W; bf16* Wt; int N;
    if (bid < 512)      { W = Wkv_;  Wt = dkv; N = 2048; }
    else if (bid < 768) { W = Wrel_; Wt = dr;  N = 1024; bid -= 512; }
    else                { W = Wq_;   Wt = dq;  N = 1024; bid -= 768; }
    const int nb = N / 64;
    tcvt_tile(W, Wt, DMOD, N, (bid % nb) * 64, (bid / nb) * 64, threadIdx.x, tile);
}

// ---------------- 128x128 GEMM body (dbuf + T2 swizzle), verified path ------
template<int SPLITS, bool RELU, typename TOUT>
__device__ __forceinline__ void gemm128_body(
    const bf16* __restrict__ A, const bf16* __restrict__ Bt,
    const float* __restrict__ bias, TOUT* __restrict__ Cbase,
    int M, int N, int K, int bx, int by, int bz,
    bf16* __restrict__ As, bf16* __restrict__ Bs)
{
    const int tid  = threadIdx.x;
    const int wave = tid >> 6, lane = tid & 63;
    const int m0 = by * 128, n0 = bx * 128;
    const int g = lane >> 4, c16 = lane & 15;
    const int wr = (wave >> 1) * 64, wc = (wave & 1) * 64;

    const int klen   = K / SPLITS;
    const int kstart = bz * klen;
    TOUT* C = Cbase + (size_t)bz * M * N;

    f32x4 acc[4][4];
    #pragma unroll
    for (int mi = 0; mi < 4; mi++)
        #pragma unroll
        for (int ni = 0; ni < 4; ni++) acc[mi][ni] = (f32x4)(0.f);

    const int r0 = (wave << 5) + (lane >> 3);
    const int cc = (((lane & 7) ^ (lane >> 3)) << 3);
    const bf16* agp = A  + (size_t)(m0 + r0) * K + kstart + cc;
    const bf16* bgp = Bt + (size_t)(n0 + r0) * K + kstart + cc;
    const int lb = wave * 2048;

    #pragma unroll
    for (int q = 0; q < 4; q++) {
        gload_lds16(agp + (size_t)(q * 8) * K, As + lb + q * 512);
        gload_lds16(bgp + (size_t)(q * 8) * K, Bs + lb + q * 512);
    }

    int cur = 0;
    for (int k0 = 0; k0 < klen; k0 += 64) {
        if (k0 + 64 < klen) {
            #pragma unroll
            for (int q = 0; q < 4; q++) {
                gload_lds16(agp + k0 + 64 + (size_t)(q * 8) * K,
                            As + (cur ^ 1) * 8192 + lb + q * 512);
                gload_lds16(bgp + k0 + 64 + (size_t)(q * 8) * K,
                            Bs + (cur ^ 1) * 8192 + lb + q * 512);
            }
            asm volatile("s_waitcnt vmcnt(8)" ::: "memory");
        } else {
            asm volatile("s_waitcnt vmcnt(0)" ::: "memory");
        }
        __builtin_amdgcn_s_barrier();
        short8 af[4][2], bfr[4][2];
        #pragma unroll
        for (int mi = 0; mi < 4; mi++) {
            const int row = wr + mi * 16 + c16;
            af[mi][0] = *(const short8*)&As[cur * 8192 + SWZ(row, g * 8)];
            af[mi][1] = *(const short8*)&As[cur * 8192 + SWZ(row, 32 + g * 8)];
        }
        #pragma unroll
        for (int ni = 0; ni < 4; ni++) {
            const int row = wc + ni * 16 + c16;
            bfr[ni][0] = *(const short8*)&Bs[cur * 8192 + SWZ(row, g * 8)];
            bfr[ni][1] = *(const short8*)&Bs[cur * 8192 + SWZ(row, 32 + g * 8)];
        }
        #pragma unroll
        for (int mi = 0; mi < 4; mi++)
            #pragma unroll
            for (int ni = 0; ni < 4; ni++) {
                acc[mi][ni] = __builtin_amdgcn_mfma_f32_16x16x32_bf16(
                                  af[mi][0], bfr[ni][0], acc[mi][ni], 0, 0, 0);
                acc[mi][ni] = __builtin_amdgcn_mfma_f32_16x16x32_bf16(
                                  af[mi][1], bfr[ni][1], acc[mi][ni], 0, 0, 0);
            }
        __builtin_amdgcn_s_barrier();
        cur ^= 1;
    }

    const int crow = g * 4;
    #pragma unroll
    for (int ni = 0; ni < 4; ni++) {
        const int n = n0 + wc + ni * 16 + c16;
        const float bv = (SPLITS == 1 && bias) ? bias[n] : 0.f;
        #pragma unroll
        for (int mi = 0; mi < 4; mi++) {
            #pragma unroll
            for (int reg = 0; reg < 4; reg++) {
                const int m = m0 + wr + mi * 16 + crow + reg;
                float v = acc[mi][ni][reg] + bv;
                if (RELU) v = fmaxf(v, 0.f);
                stf(C + (size_t)m * N + n, v);
            }
        }
    }
}

template<int SPLITS, bool RELU, typename TOUT>
__global__ __launch_bounds__(256)
void mgemm128_k(const bf16* __restrict__ A, const bf16* __restrict__ Bt,
                const float* __restrict__ bias, TOUT* __restrict__ Cbase,
                int M, int N, int K)
{
    __shared__ alignas(16) bf16 As[2 * 128 * 64];
    __shared__ alignas(16) bf16 Bs[2 * 128 * 64];
    gemm128_body<SPLITS, RELU, TOUT>(A, Bt, bias, Cbase, M, N, K,
                                     blockIdx.x, blockIdx.y, blockIdx.z, As, Bs);
}

// fused kv/r/q projections: one 896-block dispatch (512 kv + 256 r + 128 q)
__global__ __launch_bounds__(256)
void proj3_k(const bf16* __restrict__ catc, const bf16* __restrict__ wkvt,
             bf16* __restrict__ kvb,
             const bf16* __restrict__ posc, const bf16* __restrict__ wrelt,
             bf16* __restrict__ rb,
             const bf16* __restrict__ xb, const bf16* __restrict__ wqt,
             float* __restrict__ qb)
{
    __shared__ alignas(16) bf16 As[2 * 128 * 64];
    __shared__ alignas(16) bf16 Bs[2 * 128 * 64];
    int bid = blockIdx.x;
    if (bid < 512) {
        gemm128_body<1, false, bf16>(catc, wkvt, nullptr, kvb,
                                     TKEY * NBAT, 2 * HDIM, DMOD,
                                     bid & 15, bid >> 4, 0, As, Bs);
    } else if (bid < 768) {
        bid -= 512;
        gemm128_body<1, false, bf16>(posc, wrelt, nullptr, rb,
                                     TKEY * NBAT, HDIM, DMOD,
                                     bid & 7, bid >> 3, 0, As, Bs);
    } else {
        bid -= 768;
        gemm128_body<1, false, float>(xb, wqt, nullptr, qb,
                                      LQ * NBAT, HDIM, DMOD,
                                      bid & 7, bid >> 3, 0, As, Bs);
    }
}

// ---------------- MFMA GEMM, 64x64 tile (fallback path, fp32 weights) ----------------
template<typename TA, typename TOUT, bool RELU>
__global__ __launch_bounds__(256)
void mgemm64_k(const TA* __restrict__ A0, const TA* __restrict__ A1, int rowsplit,
               const float* __restrict__ Bw, const float* __restrict__ bias,
               TOUT* __restrict__ C, int M, int N, int K)
{
    __shared__ alignas(16) bf16 As[64][72];
    __shared__ alignas(16) bf16 Bs[64][72];
    const int tid  = threadIdx.x;
    const int m0   = blockIdx.y * 64;
    const int n0   = blockIdx.x * 64;
    const int wave = tid >> 6, lane = tid & 63;
    const int g = lane >> 4, c16 = lane & 15;

    f32x4 acc[4];
    #pragma unroll
    for (int nt = 0; nt < 4; nt++) acc[nt] = (f32x4)(0.f);

    const int ar = tid >> 2, akc = (tid & 3) * 16;
    const int grow = m0 + ar;
    const TA* Arow = (grow < rowsplit) ? (A0 + (size_t)grow * K)
                                       : (A1 + (size_t)(grow - rowsplit) * K);
    const int bn = tid & 63, bkb = (tid >> 6) * 16;
    const float* Bcol = Bw + n0 + bn;

    for (int k0 = 0; k0 < K; k0 += 64) {
        cpy4(&As[ar][akc],      Arow + k0 + akc);
        cpy4(&As[ar][akc + 4],  Arow + k0 + akc + 4);
        cpy4(&As[ar][akc + 8],  Arow + k0 + akc + 8);
        cpy4(&As[ar][akc + 12], Arow + k0 + akc + 12);
        {
            bf16 t16[16];
            #pragma unroll
            for (int e = 0; e < 16; e++)
                t16[e] = __float2bfloat16(Bcol[(size_t)(k0 + bkb + e) * N]);
            *(uint4*)&Bs[bn][bkb]     = *(uint4*)&t16[0];
            *(uint4*)&Bs[bn][bkb + 8] = *(uint4*)&t16[8];
        }
        __syncthreads();
        const short8 a0 = *(const short8*)&As[wave * 16 + c16][g * 8];
        const short8 a1 = *(const short8*)&As[wave * 16 + c16][32 + g * 8];
        #pragma unroll
        for (int nt = 0; nt < 4; nt++) {
            acc[nt] = __builtin_amdgcn_mfma_f32_16x16x32_bf16(
                          a0, *(const short8*)&Bs[nt * 16 + c16][g * 8], acc[nt], 0, 0, 0);
            acc[nt] = __builtin_amdgcn_mfma_f32_16x16x32_bf16(
                          a1, *(const short8*)&Bs[nt * 16 + c16][32 + g * 8], acc[nt], 0, 0, 0);
        }
        __syncthreads();
    }

    const int crow = (lane >> 4) * 4, ccol = lane & 15;
    #pragma unroll
    for (int nt = 0; nt < 4; nt++) {
        const int n = n0 + nt * 16 + ccol;
        const float bv = bias ? bias[n] : 0.f;
        #pragma unroll
        for (int rr = 0; rr < 4; rr++) {
            const int m = m0 + wave * 16 + crow + rr;
            float v = acc[nt][rr] + bv;
            if (RELU) v = fmaxf(v, 0.f);
            stf(C + (size_t)m * N + n, v);
        }
    }
}

union Frag8 { bf16 h[8]; short8 v; };

// ============ single-sweep online-softmax MFMA attention (verified 133us config) =====
// Direct LDS staging (2 barriers/tile), separate Vt buffer, itile long/short pairing,
// packed fp16 score cache (slot p = c16*4 + nt, col j = (p&3)*16 + (p>>2)).
template<bool WRSC>
__global__ __launch_bounds__(256)
void flash_attn_k(const float* __restrict__ q, const bf16* __restrict__ kv,
                  const bf16* __restrict__ rg, const float* __restrict__ ub,
                  const float* __restrict__ vb,
                  float* __restrict__ m_arr, float* __restrict__ l_arr,
                  bf16* __restrict__ vec, __half* __restrict__ scr)
{
    __shared__ alignas(16) bf16 Ks[64][72];
    __shared__ alignas(16) bf16 Rs[128][72];
    __shared__ alignas(16) bf16 Vt[64][72];
    __shared__ alignas(16) bf16 BDs[64][136];

    const int itile = (blockIdx.y < (NBAT * NHEAD / 2))
                          ? blockIdx.x : (gridDim.x - 1 - blockIdx.x);
    const int i0 = itile * 64;
    const int bh = blockIdx.y;
    const int b = bh >> 4, h = bh & 15;
    const int tid = threadIdx.x;
    const int wave = tid >> 6, lane = tid & 63;
    const int g = lane >> 4, c16 = lane & 15;
    const int dib = wave * 16 + g * 4;
    const int tbase = itile * 17 + itile * (itile - 1) / 2;

    Frag8 fu0, fu1, fv0, fv1;
    {
        const float* qrow = q + ((size_t)(i0 + wave * 16 + c16) * NBAT + b) * HDIM + h * DHEAD;
        const float* ubp = ub + h * DHEAD;
        const float* vbp = vb + h * DHEAD;
        #pragma unroll
        for (int e = 0; e < 8; e++) {
            float q0 = qrow[g * 8 + e], q1 = qrow[32 + g * 8 + e];
            fu0.h[e] = __float2bfloat16(q0 + ubp[g * 8 + e]);
            fu1.h[e] = __float2bfloat16(q1 + ubp[32 + g * 8 + e]);
            fv0.h[e] = __float2bfloat16(q0 + vbp[g * 8 + e]);
            fv1.h[e] = __float2bfloat16(q1 + vbp[32 + g * 8 + e]);
        }
    }

    float mrow[4] = {-3e38f, -3e38f, -3e38f, -3e38f};
    float lrow[4] = {0.f, 0.f, 0.f, 0.f};
    f32x4 Oacc[4];
    #pragma unroll
    for (int nt = 0; nt < 4; nt++) Oacc[nt] = (f32x4)(0.f);

    const int ntiles = i0 / 64 + 17;

    for (int t = 0; t < ntiles; t++) {
        const int j0 = t * 64;
        const int jj0 = j0 + (LQ - 64) - i0;
        __half* scp = nullptr;
        if (WRSC) scp = scr + ((size_t)bh * NVTILE + tbase + t) * 4096;
        // ---- phase 1: stage K, R, V ----
        {
            const int row = tid >> 2, dbase = (tid & 3) * 16;
            const bf16* src = kv + ((size_t)(j0 + row) * NBAT + b) * (2 * HDIM)
                                 + h * DHEAD + dbase;
            *(uint4*)&Ks[row][dbase]     = *(const uint4*)src;
            *(uint4*)&Ks[row][dbase + 8] = *(const uint4*)(src + 8);
        }
        {
            const int row = tid >> 1, dbase = (tid & 1) * 32;
            const int jj = jj0 + row;
            if (jj < TKEY) {
                const bf16* src = rg + ((size_t)jj * NBAT + b) * HDIM + h * DHEAD + dbase;
                #pragma unroll
                for (int u = 0; u < 4; u++)
                    *(uint4*)&Rs[row][dbase + u * 8] = *(const uint4*)(src + u * 8);
            } else {
                const uint4 z = make_uint4(0, 0, 0, 0);
                #pragma unroll
                for (int u = 0; u < 4; u++)
                    *(uint4*)&Rs[row][dbase + u * 8] = z;
            }
        }
        {
            const int j = tid & 63, dbase = (tid >> 6) * 16;
            const bf16* src = kv + ((size_t)(j0 + j) * NBAT + b) * (2 * HDIM)
                                 + HDIM + h * DHEAD + dbase;
            bf16 tmp[16];
            *(uint4*)&tmp[0] = *(const uint4*)src;
            *(uint4*)&tmp[8] = *(const uint4*)(src + 8);
            #pragma unroll
            for (int e = 0; e < 16; e++) Vt[dbase + e][j] = tmp[e];
        }
        __syncthreads();
        // ---- QK^T (AC) ----
        f32x4 ac[4];
        #pragma unroll
        for (int nt = 0; nt < 4; nt++) {
            ac[nt] = (f32x4)(0.f);
            ac[nt] = __builtin_amdgcn_mfma_f32_16x16x32_bf16(
                         fu0.v, *(const short8*)&Ks[nt * 16 + c16][g * 8], ac[nt], 0, 0, 0);
            ac[nt] = __builtin_amdgcn_mfma_f32_16x16x32_bf16(
                         fu1.v, *(const short8*)&Ks[nt * 16 + c16][32 + g * 8], ac[nt], 0, 0, 0);
        }
        // ---- BD (rel) -> BDs stripe (intra-wave round-trip) ----
        #pragma unroll
        for (int nt = 0; nt < 8; nt++) {
            f32x4 bd = (f32x4)(0.f);
            bd = __builtin_amdgcn_mfma_f32_16x16x32_bf16(
                     fv0.v, *(const short8*)&Rs[nt * 16 + c16][g * 8], bd, 0, 0, 0);
            bd = __builtin_amdgcn_mfma_f32_16x16x32_bf16(
                     fv1.v, *(const short8*)&Rs[nt * 16 + c16][32 + g * 8], bd, 0, 0, 0);
            #pragma unroll
            for (int reg = 0; reg < 4; reg++)
                BDs[dib + reg][nt * 16 + c16] = __float2bfloat16(bd[reg]);
        }
        // ---- scores (+ packed fp16 cache) + online softmax ----
        float sv[4][4];
        #pragma unroll
        for (int reg = 0; reg < 4; reg++) {
            const int di = dib + reg;
            const int colbase = 63 - di;
            __half hv[4];
            #pragma unroll
            for (int nt = 0; nt < 4; nt++) {
                const int dj = nt * 16 + c16;
                float s = (ac[nt][reg] +
                           __bfloat162float(BDs[di][colbase + dj])) * SCALE_F;
                if (j0 + dj > i0 + di + MEMLEN) s = -1e30f;
                sv[nt][reg] = s;
                if (WRSC) hv[nt] = __float2half(s);
            }
            if (WRSC) *(uint2*)&scp[di * 64 + c16 * 4] = *(uint2*)hv;
        }
        #pragma unroll
        for (int reg = 0; reg < 4; reg++) {
            float tm = fmaxf(fmaxf(sv[0][reg], sv[1][reg]),
                             fmaxf(sv[2][reg], sv[3][reg]));
            #pragma unroll
            for (int mk = 1; mk < 16; mk <<= 1)
                tm = fmaxf(tm, __shfl_xor(tm, mk));
            const float nm = fmaxf(mrow[reg], tm);
            const float alpha = __expf(mrow[reg] - nm);
            float ev[4];
            #pragma unroll
            for (int nt = 0; nt < 4; nt++) ev[nt] = __expf(sv[nt][reg] - nm);
            float ps = ev[0] + ev[1] + ev[2] + ev[3];
            #pragma unroll
            for (int mk = 1; mk < 16; mk <<= 1)
                ps += __shfl_xor(ps, mk);
            lrow[reg] = lrow[reg] * alpha + ps;
            mrow[reg] = nm;
            #pragma unroll
            for (int nt = 0; nt < 4; nt++) {
                Oacc[nt][reg] *= alpha;
                BDs[dib + reg][nt * 16 + c16] = __float2bfloat16(ev[nt]);
            }
        }
        // ---- PV ----
        short8 p0 = *(const short8*)&BDs[wave * 16 + c16][g * 8];
        short8 p1 = *(const short8*)&BDs[wave * 16 + c16][32 + g * 8];
        #pragma unroll
        for (int nt = 0; nt < 4; nt++) {
            Oacc[nt] = __builtin_amdgcn_mfma_f32_16x16x32_bf16(
                           p0, *(const short8*)&Vt[nt * 16 + c16][g * 8], Oacc[nt], 0, 0, 0);
            Oacc[nt] = __builtin_amdgcn_mfma_f32_16x16x32_bf16(
                           p1, *(const short8*)&Vt[nt * 16 + c16][32 + g * 8], Oacc[nt], 0, 0, 0);
        }
        __syncthreads();
    }

    float invl[4];
    #pragma unroll
    for (int reg = 0; reg < 4; reg++) invl[reg] = 1.f / lrow[reg];
    #pragma unroll
    for (int nt = 0; nt < 4; nt++)
        #pragma unroll
        for (int reg = 0; reg < 4; reg++)
            vec[((size_t)(i0 + dib + reg) * NBAT + b) * HDIM + h * DHEAD + nt * 16 + c16]
                = __float2bfloat16(Oacc[nt][reg] * invl[reg]);
    if (c16 == 0) {
        #pragma unroll
        for (int reg = 0; reg < 4; reg++) {
            const int idx = ((i0 + dib + reg) * NBAT + b) * NHEAD + h;
            m_arr[idx] = mrow[reg];
            l_arr[idx] = lrow[reg];
        }
    }
}

// ============ attn matrix from cached scores — no atomics, self-zeroing ==========
// grid (512, 2): bx = it*32 + jt covers ALL tiles; invalid tiles write zeros directly
// (no separate fill_zero pass). y = row-half.
__global__ __launch_bounds__(256)
void attn_sum2_k(const __half* __restrict__ scr, const float* __restrict__ m_arr,
                 const float* __restrict__ l_arr, float* __restrict__ attn)
{
    const int it = blockIdx.x >> 5, jt = blockIdx.x & 31;
    const int i0 = it * 64, j0 = jt * 64;
    const int tid = threadIdx.x;
    const int row = blockIdx.y * 32 + (tid >> 3);
    const int pb = (tid & 7) * 8;
    const int i = i0 + row;

    if (jt > it + 16) {     // fully-masked tile
        #pragma unroll
        for (int e = 0; e < 8; e++) {
            const int p = pb + e;
            const int j = (p & 3) * 16 + (p >> 2);
            attn[(size_t)i * TKEY + j0 + j] = 0.f;
        }
        return;
    }
    const int ft = it * 17 + it * (it - 1) / 2 + jt;   // flat valid-tile index

    float acc[8] = {0.f, 0.f, 0.f, 0.f, 0.f, 0.f, 0.f, 0.f};
    for (int bh = 0; bh < NBAT * NHEAD; bh++) {
        const int b = bh >> 4, h = bh & 15;
        const __half* sp = scr + ((size_t)bh * NVTILE + ft) * 4096 + row * 64 + pb;
        const int idx = (i * NBAT + b) * NHEAD + h;
        const float mi = m_arr[idx];
        const float il = 1.f / l_arr[idx];
        union { uint4 v; __half hx[8]; } u;
        u.v = *(const uint4*)sp;
        #pragma unroll
        for (int e = 0; e < 8; e++)
            acc[e] += __expf(__half2float(u.hx[e]) - mi) * il;
    }
    const float inv = 1.f / (NBAT * NHEAD);
    #pragma unroll
    for (int e = 0; e < 8; e++) {
        const int p = pb + e;
        const int j = (p & 3) * 16 + (p >> 2);
        attn[(size_t)i * TKEY + j0 + j] = acc[e] * inv;
    }
}

// ============ attn matrix via MFMA (mid-tier fallback; atomic-accumulating) ==========
__global__ __launch_bounds__(256)
void attn_mat4_k(const float* __restrict__ q, const bf16* __restrict__ kv,
                 const bf16* __restrict__ rg, const float* __restrict__ ub,
                 const float* __restrict__ vb, const float* __restrict__ m_arr,
                 const float* __restrict__ l_arr, float* __restrict__ attn)
{
    int f = blockIdx.x, it = 0, base = 0;
    for (it = 0; it < 16; it++) {
        const int cnt = it + 17;
        if (f < base + cnt) break;
        base += cnt;
    }
    const int i0 = it * 64;
    const int j0 = (f - base) * 64;
    const int bhb = blockIdx.y * 16;

    __shared__ alignas(16) bf16 Ks[64][72];
    __shared__ alignas(16) bf16 Rs[128][72];
    __shared__ alignas(16) bf16 BDs[64][136];
    const int tid = threadIdx.x;
    const int wave = tid >> 6, lane = tid & 63;
    const int g = lane >> 4, c16 = lane & 15;
    const int dib = wave * 16 + g * 4;
    const int jj0 = j0 + (LQ - 64) - i0;
    float psum[4][4] = {};

    for (int bh = bhb; bh < bhb + 16; bh++) {
        const int b = bh >> 4, h = bh & 15;
        Frag8 fu0, fu1, fv0, fv1;
        {
            const float* qrow = q + ((size_t)(i0 + wave * 16 + c16) * NBAT + b) * HDIM + h * DHEAD;
            const float* ubp = ub + h * DHEAD;
            const float* vbp = vb + h * DHEAD;
            #pragma unroll
            for (int e = 0; e < 8; e++) {
                float q0 = qrow[g * 8 + e], q1 = qrow[32 + g * 8 + e];
                fu0.h[e] = __float2bfloat16(q0 + ubp[g * 8 + e]);
                fu1.h[e] = __float2bfloat16(q1 + ubp[32 + g * 8 + e]);
                fv0.h[e] = __float2bfloat16(q0 + vbp[g * 8 + e]);
                fv1.h[e] = __float2bfloat16(q1 + vbp[32 + g * 8 + e]);
            }
        }
        {
            const int row = tid >> 2, dbase = (tid & 3) * 16;
            const bf16* src = kv + ((size_t)(j0 + row) * NBAT + b) * (2 * HDIM)
                                 + h * DHEAD + dbase;
            *(uint4*)&Ks[row][dbase]     = *(const uint4*)src;
            *(uint4*)&Ks[row][dbase + 8] = *(const uint4*)(src + 8);
        }
        {
            const int row = tid >> 1, dbase = (tid & 1) * 32;
            const int jj = jj0 + row;
            if (jj < TKEY) {
                const bf16* src = rg + ((size_t)jj * NBAT + b) * HDIM + h * DHEAD + dbase;
                #pragma unroll
                for (int u = 0; u < 4; u++)
                    *(uint4*)&Rs[row][dbase + u * 8] = *(const uint4*)(src + u * 8);
            } else {
                const uint4 z = make_uint4(0, 0, 0, 0);
                #pragma unroll
                for (int u = 0; u < 4; u++)
                    *(uint4*)&Rs[row][dbase + u * 8] = z;
            }
        }
        __syncthreads();
        f32x4 ac[4];
        #pragma unroll
        for (int nt = 0; nt < 4; nt++) {
            ac[nt] = (f32x4)(0.f);
            ac[nt] = __builtin_amdgcn_mfma_f32_16x16x32_bf16(
                         fu0.v, *(const short8*)&Ks[nt * 16 + c16][g * 8], ac[nt], 0, 0, 0);
            ac[nt] = __builtin_amdgcn_mfma_f32_16x16x32_bf16(
                         fu1.v, *(const short8*)&Ks[nt * 16 + c16][32 + g * 8], ac[nt], 0, 0, 0);
        }
        #pragma unroll
        for (int nt = 0; nt < 8; nt++) {
            f32x4 bd = (f32x4)(0.f);
            bd = __builtin_amdgcn_mfma_f32_16x16x32_bf16(
                     fv0.v, *(const short8*)&Rs[nt * 16 + c16][g * 8], bd, 0, 0, 0);
            bd = __builtin_amdgcn_mfma_f32_16x16x32_bf16(
                     fv1.v, *(const short8*)&Rs[nt * 16 + c16][32 + g * 8], bd, 0, 0, 0);
            #pragma unroll
            for (int reg = 0; reg < 4; reg++)
                BDs[dib + reg][nt * 16 + c16] = __float2bfloat16(bd[reg]);
        }
        #pragma unroll
        for (int reg = 0; reg < 4; reg++) {
            const int di = dib + reg;
            const int colbase = 63 - di;
            const int idx = ((i0 + di) * NBAT + b) * NHEAD + h;
            const float mi = m_arr[idx];
            const float il = 1.f / l_arr[idx];
            #pragma unroll
            for (int nt = 0; nt < 4; nt++) {
                const int dj = nt * 16 + c16;
                float s = (ac[nt][reg] +
                           __bfloat162float(BDs[di][colbase + dj])) * SCALE_F;
                float p = (j0 + dj > i0 + di + MEMLEN) ? 0.f : __expf(s - mi) * il;
                psum[nt][reg] += p;
            }
        }
        __syncthreads();
    }
    const float inv = 1.f / (NBAT * NHEAD);
    #pragma unroll
    for (int nt = 0; nt < 4; nt++)
        #pragma unroll
        for (int reg = 0; reg < 4; reg++)
            atomicAdd(&attn[(size_t)(i0 + dib + reg) * TKEY + j0 + nt * 16 + c16],
                      psum[nt][reg] * inv);
}

// ---------------- fused residual + LayerNorm ----------------
template<typename T1, typename T2, typename TOUT>
__global__ __launch_bounds__(256)
void ln_k(const T1* __restrict__ a, const T2* __restrict__ c,
          const float* __restrict__ g, const float* __restrict__ bb,
          TOUT* __restrict__ out)
{
    const int row = blockIdx.x;
    const int tid = threadIdx.x;
    const size_t base = (size_t)row * DMOD;
    float vals[4];
    float s = 0.f, sq = 0.f;
    #pragma unroll
    for (int t = 0; t < 4; t++) {
        const int dcol = tid + t * 256;
        float v = ldf(a + base + dcol) + ldf(c + base + dcol);
        vals[t] = v; s += v; sq += v * v;
    }
    __shared__ float rs[256], rq[256];
    rs[tid] = s; rq[tid] = sq;
    __syncthreads();
    for (int st = 128; st > 0; st >>= 1) {
        if (tid < st) { rs[tid] += rs[tid + st]; rq[tid] += rq[tid + st]; }
        __syncthreads();
    }
    const float mean = rs[0] / DMOD;
    const float var = rq[0] / DMOD - mean * mean;
    const float rstd = rsqrtf(fmaxf(var, 0.f) + EPS_F);
    #pragma unroll
    for (int t = 0; t < 4; t++) {
        const int dcol = tid + t * 256;
        float v = (vals[t] - mean) * rstd * g[dcol] + bb[dcol];
        stf(out + base + dcol, v);
    }
}

// ---------------- residual + NP split-K fp32 partials (+optional bias) + LayerNorm ----
template<typename TA, int NP, bool HASB, typename TOUT>
__global__ __launch_bounds__(256)
void lnp_k(const TA* __restrict__ a, const float* __restrict__ part, size_t pstride,
           const float* __restrict__ biasvec, const float* __restrict__ g,
           const float* __restrict__ bb, TOUT* __restrict__ out)
{
    const int row = blockIdx.x;
    const int tid = threadIdx.x;
    const size_t base = (size_t)row * DMOD;
    float vals[4];
    float s = 0.f, sq = 0.f;
    #pragma unroll
    for (int t = 0; t < 4; t++) {
        const int dcol = tid + t * 256;
        float v = ldf(a + base + dcol);
        #pragma unroll
        for (int p = 0; p < NP; p++) v += part[(size_t)p * pstride + base + dcol];
        if (HASB) v += biasvec[dcol];
        vals[t] = v; s += v; sq += v * v;
    }
    __shared__ float rs[256], rq[256];
    rs[tid] = s; rq[tid] = sq;
    __syncthreads();
    for (int st = 128; st > 0; st >>= 1) {
        if (tid < st) { rs[tid] += rs[tid + st]; rq[tid] += rq[tid + st]; }
        __syncthreads();
    }
    const float mean = rs[0] / DMOD;
    const float var = rq[0] / DMOD - mean * mean;
    const float rstd = rsqrtf(fmaxf(var, 0.f) + EPS_F);
    #pragma unroll
    for (int t = 0; t < 4; t++) {
        const int dcol = tid + t * 256;
        float v = (vals[t] - mean) * rstd * g[dcol] + bb[dcol];
        stf(out + base + dcol, v);
    }
}

__global__ void fill_zero_k(float* __restrict__ p, int n) {
    int i = blockIdx.x * 256 + threadIdx.x;
    if (i < n) p[i] = 0.f;
}

extern "C" void kernel_launch(void* const* d_in, const int* in_sizes, int n_in,
                              void* d_out, int out_size, void* d_ws, size_t ws_size,
                              hipStream_t stream)
{
    const float* x    = (const float*)d_in[0];
    const float* pos  = (const float*)d_in[1];
    const float* ub   = (const float*)d_in[2];
    const float* vb   = (const float*)d_in[3];
    const float* memp = (const float*)d_in[4];
    const float* Wq   = (const float*)d_in[5];
    const float* Wkv  = (const float*)d_in[6];
    const float* Wo   = (const float*)d_in[7];
    const float* Wrel = (const float*)d_in[8];
    const float* ln1g = (const float*)d_in[9];
    const float* ln1b = (const float*)d_in[10];
    const float* W1   = (const float*)d_in[11];
    const float* b1   = (const float*)d_in[12];
    const float* W2   = (const float*)d_in[13];
    const float* b2   = (const float*)d_in[14];
    const float* ln2g = (const float*)d_in[15];
    const float* ln2b = (const float*)d_in[16];

    // ---- workspace, lifetime-aliased ----
    char* wsb = (char*)d_ws;
    const size_t MB = 1048576;
    bf16*  kvb   = (bf16*)(wsb + 0);
    bf16*  h1    = (bf16*)(wsb + 0);
    bf16*  rb    = (bf16*)(wsb + 16 * MB);
    bf16*  aout  = (bf16*)(wsb + 16 * MB);
    bf16*  f2o   = (bf16*)(wsb + 16 * MB);
    bf16*  out1  = (bf16*)(wsb + 20 * MB);
    bf16*  vecb  = (bf16*)(wsb + 24 * MB);
    float* m_arr = (float*)(wsb + 28 * MB);
    float* l_arr = (float*)(wsb + 28 * MB + 131072);
    const size_t ws_need_old = 28 * MB + 262144;
    bf16*  catc  = (bf16*)(wsb + 30 * MB);
    bf16*  posc  = (bf16*)(wsb + 38 * MB);
    float* part2 = (float*)(wsb + 30 * MB);
    bf16*  wscr  = (bf16*)(wsb + 46 * MB);
    const size_t ws_need_new = 54 * MB;
    __half* scrh = (__half*)(wsb + 54 * MB);   // fp16 score cache, 98 MB
    const size_t ws_need_sc = 54 * MB + (size_t)NVTILE * 32 * 4096 * 2;  // 152 MB

    float* outp  = (float*)d_out;
    float* attnp = outp + (size_t)LQ * NBAT * DMOD;
    float* qb    = outp;

    const dim3 blk(256);
    const size_t PSTRIDE = (size_t)LQ * NBAT * DMOD;
    const int NATTN = LQ * TKEY;

    if (ws_size < ws_need_old) {
        fill_zero_k<<<dim3((out_size + 255) / 256), blk, 0, stream>>>(outp, out_size);
        return;
    }

    if (ws_size >= ws_need_new) {
        // ======== fast path (best-known verified configuration) ========
        const bool useSC = (ws_size >= ws_need_sc);
        const int nCat = MEMLEN * NBAT * DMOD;
        const int nPos = TKEY * NBAT * DMOD;
        cvt3_bf16_k<<<dim3((2 * nCat + nPos) / 2048), blk, 0, stream>>>(
            memp, catc, nCat, x, catc + (size_t)nCat, nCat, pos, posc, nPos);
        tcvt3_k<<<dim3(1024), blk, 0, stream>>>(
            Wkv, wscr, Wrel, wscr + (size_t)2 * MB, Wq, wscr + (size_t)3 * MB);

        proj3_k<<<dim3(896), blk, 0, stream>>>(
            catc, wscr, kvb,
            posc, wscr + (size_t)2 * MB, rb,
            catc + (size_t)nCat, wscr + (size_t)3 * MB, qb);

        if (useSC) {
            flash_attn_k<true><<<dim3(LQ / 64, NBAT * NHEAD), blk, 0, stream>>>(
                qb, kvb, rb, ub, vb, m_arr, l_arr, vecb, scrh);
            attn_sum2_k<<<dim3(512, 2), blk, 0, stream>>>(scrh, m_arr, l_arr, attnp);
        } else {
            fill_zero_k<<<dim3((NATTN + 255) / 256), blk, 0, stream>>>(attnp, NATTN);
            flash_attn_k<false><<<dim3(LQ / 64, NBAT * NHEAD), blk, 0, stream>>>(
                qb, kvb, rb, ub, vb, m_arr, l_arr, vecb, nullptr);
            attn_mat4_k<<<dim3(NVTILE, 2), blk, 0, stream>>>(
                qb, kvb, rb, ub, vb, m_arr, l_arr, attnp);
        }

        tcvt_bf16_k<<<dim3(DMOD / 64, HDIM / 64), blk, 0, stream>>>(Wo, wscr, HDIM, DMOD);
        mgemm128_k<2, false, float><<<dim3(DMOD / 128, LQ * NBAT / 128, 2), blk, 0, stream>>>(
            vecb, wscr, nullptr, part2, LQ * NBAT, DMOD, HDIM);
        lnp_k<float, 2, false, bf16><<<dim3(LQ * NBAT), blk, 0, stream>>>(
            x, part2, PSTRIDE, nullptr, ln1g, ln1b, out1);
        tcvt_bf16_k<<<dim3(DFFN / 64, DMOD / 64), blk, 0, stream>>>(W1, wscr, DMOD, DFFN);
        mgemm128_k<1, true, bf16><<<dim3(DFFN / 128, LQ * NBAT / 128, 1), blk, 0, stream>>>(
            out1, wscr, b1, h1, LQ * NBAT, DFFN, DMOD);
        tcvt_bf16_k<<<dim3(DMOD / 64, DFFN / 64), blk, 0, stream>>>(W2, wscr, DFFN, DMOD);
        mgemm128_k<2, false, float><<<dim3(DMOD / 128, LQ * NBAT / 128, 2), blk, 0, stream>>>(
            h1, wscr, nullptr, part2, LQ * NBAT, DMOD, DFFN);
        lnp_k<bf16, 2, true, float><<<dim3(LQ * NBAT), blk, 0, stream>>>(
            out1, part2, PSTRIDE, b2, ln2g, ln2b, outp);
        return;
    }

    // ======== fallback path ========
    mgemm64_k<float, bf16, false><<<dim3(2 * HDIM / 64, TKEY * NBAT / 64), blk, 0, stream>>>(
        memp, x, MEMLEN * NBAT, Wkv, nullptr, kvb, TKEY * NBAT, 2 * HDIM, DMOD);
    mgemm64_k<float, bf16, false><<<dim3(HDIM / 64, TKEY * NBAT / 64), blk, 0, stream>>>(
        pos, pos, TKEY * NBAT, Wrel, nullptr, rb, TKEY * NBAT, HDIM, DMOD);
    mgemm64_k<float, float, false><<<dim3(HDIM / 64, LQ * NBAT / 64), blk, 0, stream>>>(
        x, x, LQ * NBAT, Wq, nullptr, qb, LQ * NBAT, HDIM, DMOD);

    fill_zero_k<<<dim3((NATTN + 255) / 256), blk, 0, stream>>>(attnp, NATTN);
    flash_attn_k<false><<<dim3(LQ / 64, NBAT * NHEAD), blk, 0, stream>>>(
        qb, kvb, rb, ub, vb, m_arr, l_arr, vecb, nullptr);
    attn_mat4_k<<<dim3(NVTILE, 2), blk, 0, stream>>>(
        qb, kvb, rb, ub, vb, m_arr, l_arr, attnp);

    mgemm64_k<bf16, bf16, false><<<dim3(DMOD / 64, LQ * NBAT / 64), blk, 0, stream>>>(
        vecb, vecb, LQ * NBAT, Wo, nullptr, aout, LQ * NBAT, DMOD, HDIM);
    ln_k<float, bf16, bf16><<<dim3(LQ * NBAT), blk, 0, stream>>>(x, aout, ln1g, ln1b, out1);
    mgemm64_k<bf16, bf16, true><<<dim3(DFFN / 64, LQ * NBAT / 64), blk, 0, stream>>>(
        out1, out1, LQ * NBAT, W1, b1, h1, LQ * NBAT, DFFN, DMOD);
    mgemm64_k<bf16, bf16, false><<<dim3(DMOD / 64, LQ * NBAT / 64), blk, 0, stream>>>(
        h1, h1, LQ * NBAT, W2, b2, f2o, LQ * NBAT, DMOD, DFFN);
    ln_k<bf16, bf16, float><<<dim3(LQ * NBAT), blk, 0, stream>>>(out1, f2o, ln2g, ln2b, outp);
}